// Round 3
// baseline (53945.148 us; speedup 1.0000x reference)
//
#include <hip/hip_runtime.h>
#include <math.h>

// ---------------------------------------------------------------------------
// CompactVidTr forward, fp32.
// Layout: token matrices row-major [row = l*B + b][C]; l=0 is cls. B=8, C=512.
//
// Workspace (< 256 MiB):
//   X   : 3137*8 x 512  fp32   (51.4 MB)  residual stream, pooled IN PLACE
//   Ab  : 3137*8 x 512  fp32   (51.4 MB)  LN out / attention out staging
//   QKV : 3137*8 x 1536 fp32  (154.2 MB)  qkv GEMM out; reused as FFN mid
//   CLS : 8x512, IDX: 8*8*196*16 ints     (~0.8 MB)
// ---------------------------------------------------------------------------

#define BB 8
#define CC 512
#define HH 8
#define HD 64
#define WHT 196
#define NCLS 157

__device__ __forceinline__ float wave_reduce_sum(float v) {
#pragma unroll
  for (int o = 32; o > 0; o >>= 1) v += __shfl_down(v, o, 64);
  return v;
}
__device__ __forceinline__ float wave_reduce_max(float v) {
#pragma unroll
  for (int o = 32; o > 0; o >>= 1) v = fmaxf(v, __shfl_down(v, o, 64));
  return v;
}

// ---------------------------------------------------------------------------
// Patch-embed conv
// ---------------------------------------------------------------------------
__global__ __launch_bounds__(256)
void conv_kernel(const float* __restrict__ src, const float* __restrict__ cw,
                 const float* __restrict__ cb, float* __restrict__ X) {
  __shared__ float patch[8][776];
  const int tid = threadIdx.x;
  const int u0 = blockIdx.x * 8;
  for (int j = 0; j < 8; j++) {
    int u = u0 + j;
    int b = u & 7;
    int s = u >> 3;
    int tt = s / WHT;
    int w2 = s % WHT;
    int ph = w2 / 14, pw = w2 % 14;
    const float* sb = src + (size_t)b * (3 * 16 * 224 * 224) +
                      (size_t)tt * (224 * 224) + (size_t)(ph * 16) * 224 + pw * 16;
    for (int e = tid; e < 768; e += 256) {
      int ci = e >> 8;
      int rem = e & 255;
      int py = rem >> 4, px = rem & 15;
      patch[j][e] = sb[(size_t)ci * (16 * 224 * 224) + py * 224 + px];
    }
  }
  __syncthreads();
  float acc0[8] = {0, 0, 0, 0, 0, 0, 0, 0};
  float acc1[8] = {0, 0, 0, 0, 0, 0, 0, 0};
  for (int e0 = 0; e0 < 768; e0 += 4) {
    float4 w0 = *(const float4*)(cw + (size_t)tid * 768 + e0);
    float4 w1 = *(const float4*)(cw + (size_t)(tid + 256) * 768 + e0);
#pragma unroll
    for (int j = 0; j < 8; j++) {
      float4 p = *(const float4*)&patch[j][e0];
      acc0[j] += w0.x * p.x + w0.y * p.y + w0.z * p.z + w0.w * p.w;
      acc1[j] += w1.x * p.x + w1.y * p.y + w1.z * p.z + w1.w * p.w;
    }
  }
  float cb0 = cb[tid], cb1 = cb[tid + 256];
  for (int j = 0; j < 8; j++) {
    int u = u0 + j;
    X[(size_t)(8 + u) * CC + tid] = acc0[j] + cb0;
    X[(size_t)(8 + u) * CC + tid + 256] = acc1[j] + cb1;
  }
}

__global__ void cls_init_kernel(const float* __restrict__ clst, float* __restrict__ X) {
  X[(size_t)blockIdx.x * CC + threadIdx.x] = clst[threadIdx.x];
}

__global__ void copy_cls_kernel(const float* __restrict__ cls, float* __restrict__ A) {
  A[(size_t)blockIdx.x * CC + threadIdx.x] = cls[(size_t)blockIdx.x * CC + threadIdx.x];
}

// ---------------------------------------------------------------------------
// LayerNorm over C=512; one block per row; optional +pos (layer0 q-input)
// ---------------------------------------------------------------------------
__global__ __launch_bounds__(256)
void ln_kernel(const float* __restrict__ X, float* __restrict__ O,
               const float* __restrict__ w, const float* __restrict__ b,
               const float* __restrict__ pos) {
  __shared__ float red[8];
  const int row = blockIdx.x, tid = threadIdx.x;
  const float* x = X + (size_t)row * CC;
  float v0 = x[tid], v1 = x[tid + 256];
  float s = wave_reduce_sum(v0 + v1);
  if ((tid & 63) == 0) red[tid >> 6] = s;
  __syncthreads();
  float mean = (red[0] + red[1] + red[2] + red[3]) * (1.f / 512.f);
  float d0 = v0 - mean, d1 = v1 - mean;
  float vs = wave_reduce_sum(d0 * d0 + d1 * d1);
  if ((tid & 63) == 0) red[4 + (tid >> 6)] = vs;
  __syncthreads();
  float var = (red[4] + red[5] + red[6] + red[7]) * (1.f / 512.f);
  float inv = 1.0f / sqrtf(var + 1e-5f);
  float o0 = d0 * inv * w[tid] + b[tid];
  float o1 = d1 * inv * w[tid + 256] + b[tid + 256];
  if (pos) {
    const float* pr = pos + (size_t)(row >> 3) * CC;
    o0 += pr[tid];
    o1 += pr[tid + 256];
  }
  O[(size_t)row * CC + tid] = o0;
  O[(size_t)row * CC + tid + 256] = o1;
}

// ---------------------------------------------------------------------------
// Generic fp32 GEMM: C = A(M,K) @ W(K,N) + bias  [+relu] [+same-row residual]
// ---------------------------------------------------------------------------
template <int RELU, int RES>
__global__ __launch_bounds__(256)
void gemm_kernel(const float* __restrict__ A, const float* __restrict__ W,
                 const float* __restrict__ bias, float* __restrict__ Cout,
                 int M, int N, int K, const float* __restrict__ resid) {
  __shared__ float As[16][68];
  __shared__ float Wsm[16][68];
  const int tid = threadIdx.x;
  const int tx = tid & 15, ty = tid >> 4;
  const int m0 = blockIdx.x * 64, n0 = blockIdx.y * 64;
  float acc[4][4] = {};
  for (int k0 = 0; k0 < K; k0 += 16) {
    {
      int e = tid * 4;
      int m = e >> 4, kk = e & 15;
      int gm = m0 + m;
      float4 vals;
      if (gm < M)
        vals = *(const float4*)(A + (size_t)gm * K + k0 + kk);
      else
        vals = make_float4(0.f, 0.f, 0.f, 0.f);
      As[kk + 0][m] = vals.x;
      As[kk + 1][m] = vals.y;
      As[kk + 2][m] = vals.z;
      As[kk + 3][m] = vals.w;
    }
    {
      int e = tid * 4;
      int kk = e >> 6, nn = e & 63;
      float4 vals = *(const float4*)(W + (size_t)(k0 + kk) * N + n0 + nn);
      *(float4*)&Wsm[kk][nn] = vals;
    }
    __syncthreads();
#pragma unroll
    for (int kk = 0; kk < 16; kk++) {
      float4 a4 = *(const float4*)&As[kk][ty * 4];
      float4 b4 = *(const float4*)&Wsm[kk][tx * 4];
      float av[4] = {a4.x, a4.y, a4.z, a4.w};
      float bv[4] = {b4.x, b4.y, b4.z, b4.w};
#pragma unroll
      for (int i = 0; i < 4; i++)
#pragma unroll
        for (int j = 0; j < 4; j++) acc[i][j] += av[i] * bv[j];
    }
    __syncthreads();
  }
#pragma unroll
  for (int i = 0; i < 4; i++) {
    int gm = m0 + ty * 4 + i;
    if (gm >= M) continue;
#pragma unroll
    for (int j = 0; j < 4; j++) {
      int gn = n0 + tx * 4 + j;
      float v = acc[i][j] + bias[gn];
      if (RELU) v = fmaxf(v, 0.f);
      if (RES == 1) v += resid[(size_t)gm * N + gn];
      Cout[(size_t)gm * N + gn] = v;
    }
  }
}

// ---------------------------------------------------------------------------
// Class attention
// ---------------------------------------------------------------------------
__global__ __launch_bounds__(256)
void class_attn_kernel(const float* __restrict__ qkv, float* __restrict__ cls, int L) {
  __shared__ float q[64];
  __shared__ float sc[3200];
  __shared__ float red[8];
  __shared__ float pv[256];
  const int h = blockIdx.x & 7, b = blockIdx.x >> 3;
  const int tid = threadIdx.x;
  if (tid < 64) q[tid] = qkv[(size_t)b * 1536 + h * 64 + tid] * 0.125f;
  __syncthreads();
  float lmax = -3.4e38f;
  for (int l = tid; l < L; l += 256) {
    const float* kr = qkv + (size_t)(l * 8 + b) * 1536 + 512 + h * 64;
    float s = 0;
#pragma unroll
    for (int d2 = 0; d2 < 64; d2++) s += q[d2] * kr[d2];
    sc[l] = s;
    lmax = fmaxf(lmax, s);
  }
  lmax = wave_reduce_max(lmax);
  if ((tid & 63) == 0) red[tid >> 6] = lmax;
  __syncthreads();
  float gmax = fmaxf(fmaxf(red[0], red[1]), fmaxf(red[2], red[3]));
  float lsum = 0;
  for (int l = tid; l < L; l += 256) {
    float e = expf(sc[l] - gmax);
    sc[l] = e;
    lsum += e;
  }
  lsum = wave_reduce_sum(lsum);
  if ((tid & 63) == 0) red[4 + (tid >> 6)] = lsum;
  __syncthreads();
  float gsum = red[4] + red[5] + red[6] + red[7];
  const int g = tid >> 6, d = tid & 63;
  float acc = 0;
  for (int l = g; l < L; l += 4)
    acc += sc[l] * qkv[(size_t)(l * 8 + b) * 1536 + 1024 + h * 64 + d];
  pv[g * 64 + d] = acc;
  __syncthreads();
  if (g == 0) {
    float tot = pv[d] + pv[64 + d] + pv[128 + d] + pv[192 + d];
    cls[b * CC + h * 64 + d] = tot / gsum;
  }
}

// ---------------------------------------------------------------------------
// Temporal attention + sigma top-k pooling. One block per (h,b,w).
// ---------------------------------------------------------------------------
__global__ __launch_bounds__(256)
void temporal_attn_kernel(const float* __restrict__ qkv, float* __restrict__ Y,
                          int* __restrict__ idxbuf, int t, int tp, int pk) {
  __shared__ float qs[16 * 65], ks[16 * 65], vs[16 * 65];
  __shared__ float a[16 * 17];
  __shared__ float sig[16];
  __shared__ int keepf[16];
  __shared__ int klist[16];
  const int g = blockIdx.x;
  const int w = g % WHT;
  const int bb = (g / WHT) & 7;
  const int h = g / (WHT * 8);
  const int tid = threadIdx.x;
  const int td = t * 64;
  for (int e = tid; e < td; e += 256) {
    int tt = e >> 6, d = e & 63;
    size_t rb = (size_t)((1 + tt * WHT + w) * 8 + bb) * 1536 + h * 64 + d;
    qs[tt * 65 + d] = qkv[rb] * 0.125f;
    ks[tt * 65 + d] = qkv[rb + 512];
    vs[tt * 65 + d] = qkv[rb + 1024];
  }
  __syncthreads();
  if (tid < t * t) {
    int qi = tid / t, ki = tid % t;
    const float* qp = &qs[qi * 65];
    const float* kp = &ks[ki * 65];
    float s = 0;
#pragma unroll
    for (int d2 = 0; d2 < 64; d2++) s += qp[d2] * kp[d2];
    a[qi * 17 + ki] = s;
  }
  __syncthreads();
  if (tid < t) {
    float* row = &a[tid * 17];
    float m = row[0];
    for (int k2 = 1; k2 < t; k2++) m = fmaxf(m, row[k2]);
    float sum = 0;
    for (int k2 = 0; k2 < t; k2++) {
      float e2 = expf(row[k2] - m);
      row[k2] = e2;
      sum += e2;
    }
    float inv = 1.f / sum;
    for (int k2 = 0; k2 < t; k2++) row[k2] *= inv;
  }
  __syncthreads();
  if (pk > 0) {
    if (tid < t) {
      const float* row = &a[tid * 17];
      float mean = 0;
      for (int k2 = 0; k2 < t; k2++) mean += row[k2];
      mean /= (float)t;
      float var = 0;
      for (int k2 = 0; k2 < t; k2++) {
        float dl = row[k2] - mean;
        var += dl * dl;
      }
      var /= (float)(t - 1);
      sig[tid] = sqrtf(var);
    }
    __syncthreads();
    if (tid < t) {
      float sv = sig[tid];
      int r = 0;
      for (int q2 = 0; q2 < t; q2++) {
        float so = sig[q2];
        if (so > sv || (so == sv && q2 < tid)) r++;
      }
      keepf[tid] = (r < tp) ? 1 : 0;
    }
    __syncthreads();
    if (tid < t && keepf[tid]) {
      int ppos = 0;
      for (int q2 = 0; q2 < tid; q2++) ppos += keepf[q2];
      klist[ppos] = tid;
      idxbuf[((h * 8 + bb) * WHT + w) * 16 + ppos] = tid;
    }
  } else {
    if (tid < t) klist[tid] = tid;
  }
  __syncthreads();
  const int gq = tid >> 6, d = tid & 63;
  for (int qi = gq; qi < tp; qi += 4) {
    int qq = klist[qi];
    const float* arow = &a[qq * 17];
    float acc = 0;
    for (int k2 = 0; k2 < t; k2++) acc += arow[k2] * vs[k2 * 65 + d];
    Y[(size_t)((qi * WHT + w) * 8 + bb) * CC + h * 64 + d] = acc;
  }
}

// ---------------------------------------------------------------------------
// In-place temporal pooling of the residual stream X.
// ---------------------------------------------------------------------------
__global__ __launch_bounds__(256)
void pool_inplace_kernel(float* __restrict__ X, const int* __restrict__ idxbuf,
                         int tp) {
  const int b = blockIdx.x & 7;
  const int w = blockIdx.x >> 3;
  const int tid = threadIdx.x;
  const int c0 = tid, c1 = tid + 256;
  const int h0 = c0 >> 6, h1 = c1 >> 6;
  const int ib0 = ((h0 * 8 + b) * WHT + w) * 16;
  const int ib1 = ((h1 * 8 + b) * WHT + w) * 16;
  for (int q = 0; q < tp; q++) {
    int s0 = idxbuf[ib0 + q];
    int s1 = idxbuf[ib1 + q];
    size_t drow = (size_t)((1 + q * WHT + w) * 8 + b) * CC;
    if (s0 != q) {
      size_t srow = (size_t)((1 + s0 * WHT + w) * 8 + b) * CC;
      X[drow + c0] = X[srow + c0];
    }
    if (s1 != q) {
      size_t srow = (size_t)((1 + s1 * WHT + w) * 8 + b) * CC;
      X[drow + c1] = X[srow + c1];
    }
  }
}

// ---------------------------------------------------------------------------
// Spatial attention v2: one block per (h,b,t). 196 q x 196 k, d=64, fp32.
// 13 q-tiles of 16 processed in-block; K/V streamed global->LDS in 64-row
// chunks; softmax parallel (16 lanes/row, shfl_xor butterflies).
// LDS ~50 KB -> 3 blocks/CU. No register spills (acc[4] only).
// ---------------------------------------------------------------------------
__global__ __launch_bounds__(256)
void spatial_attn2_kernel(const float* __restrict__ qkv, float* __restrict__ outA) {
  __shared__ float Qs[16 * 65];
  __shared__ float Ks[64 * 65];
  __shared__ float Vs[64 * 65];
  __shared__ float S[16 * 200];
  const int blk = blockIdx.x;
  const int h = blk & 7;
  const int b = (blk >> 3) & 7;
  const int tq = blk >> 6;
  const int tid = threadIdx.x;
  const size_t base = (size_t)((size_t)tq * WHT * 8 + b) * 1536 + h * 64;

  for (int qt = 0; qt < 13; qt++) {
    __syncthreads();  // previous tile's LDS reads complete
    // load Q tile (16x64), scaled
    {
#pragma unroll
      for (int r = 0; r < 4; r++) {
        int p = tid + r * 256;
        int i = p >> 6, d = p & 63;
        int w = qt * 16 + i;
        float v = 0.f;
        if (w < WHT) v = qkv[base + (size_t)w * 8 * 1536 + d] * 0.125f;
        Qs[i * 65 + d] = v;
      }
    }
    // scores S[i][k] for all 196 keys, 64-key chunks
    for (int kc = 0; kc < WHT; kc += 64) {
      const int cn = min(64, WHT - kc);
      __syncthreads();  // prev chunk compute done / Qs visible (first iter)
#pragma unroll
      for (int r = 0; r < 16; r++) {
        int p = tid + r * 256;
        int j = p >> 6, d = p & 63;
        int krow = kc + j;
        float v = 0.f;
        if (krow < WHT) v = qkv[base + (size_t)krow * 8 * 1536 + 512 + d];
        Ks[j * 65 + d] = v;
      }
      __syncthreads();
      if (cn == 64) {
#pragma unroll
        for (int r = 0; r < 4; r++) {
          int p = tid + r * 256;
          int i = p >> 6, j = p & 63;
          const float* qp = &Qs[i * 65];
          const float* kp = &Ks[j * 65];
          float s = 0.f;
#pragma unroll
          for (int d2 = 0; d2 < 64; d2++) s += qp[d2] * kp[d2];
          S[i * 200 + kc + j] = s;
        }
      } else {
        // last chunk: cn = 4 -> 64 elems
        if (tid < 16 * 4) {
          int i = tid >> 2, j = tid & 3;
          const float* qp = &Qs[i * 65];
          const float* kp = &Ks[j * 65];
          float s = 0.f;
#pragma unroll
          for (int d2 = 0; d2 < 64; d2++) s += qp[d2] * kp[d2];
          S[i * 200 + kc + j] = s;
        }
      }
    }
    __syncthreads();
    // parallel softmax: row = tid>>4, 16 lanes per row
    {
      const int row = tid >> 4;
      const int lane = tid & 15;
      float* srow = &S[row * 200];
      float m = -3.4e38f;
      for (int j = lane; j < WHT; j += 16) m = fmaxf(m, srow[j]);
#pragma unroll
      for (int msk = 8; msk >= 1; msk >>= 1) m = fmaxf(m, __shfl_xor(m, msk, 16));
      float l = 0.f;
      for (int j = lane; j < WHT; j += 16) {
        float e = expf(srow[j] - m);
        srow[j] = e;
        l += e;
      }
#pragma unroll
      for (int msk = 8; msk >= 1; msk >>= 1) l += __shfl_xor(l, msk, 16);
      float inv = 1.f / l;
      for (int j = lane; j < WHT; j += 16) srow[j] *= inv;
    }
    // PV: thread owns rows {qg, qg+4, qg+8, qg+12} at column d
    const int qg = tid >> 6, d = tid & 63;
    float acc[4] = {0.f, 0.f, 0.f, 0.f};
    for (int vc = 0; vc < WHT; vc += 64) {
      const int cn = min(64, WHT - vc);
      __syncthreads();  // prev Vs reads done / softmax S visible (first iter)
#pragma unroll
      for (int r = 0; r < 16; r++) {
        int p = tid + r * 256;
        int j = p >> 6, dd = p & 63;
        int vrow = vc + j;
        float v = 0.f;
        if (vrow < WHT) v = qkv[base + (size_t)vrow * 8 * 1536 + 1024 + dd];
        Vs[j * 65 + dd] = v;
      }
      __syncthreads();
#pragma unroll
      for (int u = 0; u < 4; u++) {
        const float* srow = &S[(qg + 4 * u) * 200 + vc];
        float av = acc[u];
        for (int j = 0; j < cn; j++) av += srow[j] * Vs[j * 65 + d];
        acc[u] = av;
      }
    }
    // store O tile
#pragma unroll
    for (int u = 0; u < 4; u++) {
      int i = qg + 4 * u;
      int w = qt * 16 + i;
      if (w < WHT)
        outA[(size_t)((1 + tq * WHT + w) * 8 + b) * CC + h * 64 + d] = acc[u];
    }
  }
}

// ---------------------------------------------------------------------------
// Final LN (token 0 only) + classifier head
// ---------------------------------------------------------------------------
__global__ __launch_bounds__(256)
void head_kernel(const float* __restrict__ X, const float* __restrict__ enw,
                 const float* __restrict__ enb, const float* __restrict__ fcw,
                 const float* __restrict__ fcb, float* __restrict__ out) {
  __shared__ float nx[512];
  __shared__ float red[8];
  const int b = blockIdx.x, tid = threadIdx.x;
  const float* x = X + (size_t)b * CC;
  float v0 = x[tid], v1 = x[tid + 256];
  float s = wave_reduce_sum(v0 + v1);
  if ((tid & 63) == 0) red[tid >> 6] = s;
  __syncthreads();
  float mean = (red[0] + red[1] + red[2] + red[3]) * (1.f / 512.f);
  float d0 = v0 - mean, d1 = v1 - mean;
  float vs = wave_reduce_sum(d0 * d0 + d1 * d1);
  if ((tid & 63) == 0) red[4 + (tid >> 6)] = vs;
  __syncthreads();
  float var = (red[4] + red[5] + red[6] + red[7]) * (1.f / 512.f);
  float inv = 1.0f / sqrtf(var + 1e-5f);
  nx[tid] = d0 * inv * enw[tid] + enb[tid];
  nx[tid + 256] = d1 * inv * enw[tid + 256] + enb[tid + 256];
  __syncthreads();
  if (tid < NCLS) {
    float acc = fcb[tid];
    for (int c = 0; c < 512; c++) acc += nx[c] * fcw[c * NCLS + tid];
    out[b * NCLS + tid] = acc;
  }
}

// ---------------------------------------------------------------------------
extern "C" void kernel_launch(void* const* d_in, const int* in_sizes, int n_in,
                              void* d_out, int out_size, void* d_ws, size_t ws_size,
                              hipStream_t stream) {
  (void)in_sizes; (void)n_in; (void)out_size; (void)ws_size;
  const float* src  = (const float*)d_in[0];
  const float* cw   = (const float*)d_in[1];
  const float* cb   = (const float*)d_in[2];
  const float* clst = (const float*)d_in[3];
  const float* pos  = (const float*)d_in[4];
  const float* Wt   = (const float*)d_in[5];
  const float* bt   = (const float*)d_in[6];
  const float* Wsp  = (const float*)d_in[7];
  const float* bsp  = (const float*)d_in[8];
  const float* Wo   = (const float*)d_in[9];
  const float* bo   = (const float*)d_in[10];
  const float* n1w  = (const float*)d_in[11];
  const float* n1b  = (const float*)d_in[12];
  const float* n2w  = (const float*)d_in[13];
  const float* n2b  = (const float*)d_in[14];
  const float* W1   = (const float*)d_in[15];
  const float* b1   = (const float*)d_in[16];
  const float* W2   = (const float*)d_in[17];
  const float* b2   = (const float*)d_in[18];
  const float* enw  = (const float*)d_in[19];
  const float* enb  = (const float*)d_in[20];
  const float* fcw  = (const float*)d_in[21];
  const float* fcb  = (const float*)d_in[22];

  float* ws = (float*)d_ws;
  const size_t TOKR = (size_t)3137 * 8;
  float* X0  = ws;                        // TOKR*512
  float* Ab  = X0 + TOKR * 512;           // TOKR*512
  float* QKV = Ab + TOKR * 512;           // TOKR*1536 (also FFN-mid chunks)
  float* CLS = QKV + TOKR * 1536;         // 8*512
  int*   IDX = (int*)(CLS + 8 * 512);     // 8*8*196*16 ints

  conv_kernel<<<3136, 256, 0, stream>>>(src, cw, cb, X0);
  cls_init_kernel<<<8, 512, 0, stream>>>(clst, X0);

  float* Xc = X0;
  int t = 16;
  const int FFN_CHUNK = 16384;
  for (int i = 0; i < 6; i++) {
    const int pk = (i & 1) ? 2 : 0;
    const int tp = t - pk;
    const int L = 1 + t * WHT;
    const int Lo = 1 + tp * WHT;
    const int M = L * 8, Mo = Lo * 8, My = tp * WHT * 8;

    ln_kernel<<<M, 256, 0, stream>>>(Xc, Ab, n1w + (size_t)i * 512, n1b + (size_t)i * 512,
                                     (i == 0) ? pos : nullptr);
    gemm_kernel<0, 0><<<dim3((M + 63) / 64, 24), 256, 0, stream>>>(
        Ab, Wt + (size_t)i * 512 * 1536, bt + (size_t)i * 1536, QKV, M, 1536, 512,
        nullptr);
    class_attn_kernel<<<64, 256, 0, stream>>>(QKV, CLS, L);
    temporal_attn_kernel<<<HH * BB * WHT, 256, 0, stream>>>(QKV, Ab, IDX, t, tp, pk);
    gemm_kernel<0, 0><<<dim3((My + 63) / 64, 24), 256, 0, stream>>>(
        Ab, Wsp + (size_t)i * 512 * 1536, bsp + (size_t)i * 1536, QKV, My, 1536, 512,
        nullptr);
    copy_cls_kernel<<<8, 512, 0, stream>>>(CLS, Ab);
    spatial_attn2_kernel<<<64 * tp, 256, 0, stream>>>(QKV, Ab);
    if (pk > 0)
      pool_inplace_kernel<<<8 * WHT, 256, 0, stream>>>(Xc, IDX, tp);
    gemm_kernel<0, 1><<<dim3((Mo + 63) / 64, 8), 256, 0, stream>>>(
        Ab, Wo + (size_t)i * 512 * 512, bo + (size_t)i * 512, Xc, Mo, 512, 512, Xc);
    ln_kernel<<<Mo, 256, 0, stream>>>(Xc, Ab, n2w + (size_t)i * 512, n2b + (size_t)i * 512,
                                      nullptr);
    for (int off = 0; off < Mo; off += FFN_CHUNK) {
      int R = Mo - off;
      if (R > FFN_CHUNK) R = FFN_CHUNK;
      gemm_kernel<1, 0><<<dim3((R + 63) / 64, 32), 256, 0, stream>>>(
          Ab + (size_t)off * 512, W1 + (size_t)i * 512 * 2048, b1 + (size_t)i * 2048,
          QKV, R, 2048, 512, nullptr);
      gemm_kernel<0, 1><<<dim3((R + 63) / 64, 8), 256, 0, stream>>>(
          QKV, W2 + (size_t)i * 2048 * 512, b2 + (size_t)i * 512,
          Xc + (size_t)off * 512, R, 512, 2048, Xc + (size_t)off * 512);
    }
    t = tp;
  }
  head_kernel<<<8, 256, 0, stream>>>(Xc, enw, enb, fcw, fcb, (float*)d_out);
}

// Round 4
// 19519.408 us; speedup vs baseline: 2.7637x; 2.7637x over previous
//
#include <hip/hip_runtime.h>
#include <math.h>

// ---------------------------------------------------------------------------
// CompactVidTr forward, fp32.
// Layout: token matrices row-major [row = l*B + b][C]; l=0 is cls. B=8, C=512.
//
// Workspace (< 256 MiB):
//   X   : 3137*8 x 512  fp32   (51.4 MB)  residual stream, pooled IN PLACE
//   Ab  : 3137*8 x 512  fp32   (51.4 MB)  LN out / attention out staging
//   QKV : 3137*8 x 1536 fp32  (154.2 MB)  qkv GEMM out; reused as FFN mid
//   CLS : 8x512, IDX: 8*8*196*16 ints     (~0.8 MB)
// ---------------------------------------------------------------------------

#define BB 8
#define CC 512
#define HH 8
#define HD 64
#define WHT 196
#define NCLS 157

__device__ __forceinline__ float wave_reduce_sum(float v) {
#pragma unroll
  for (int o = 32; o > 0; o >>= 1) v += __shfl_down(v, o, 64);
  return v;
}
__device__ __forceinline__ float wave_reduce_max(float v) {
#pragma unroll
  for (int o = 32; o > 0; o >>= 1) v = fmaxf(v, __shfl_down(v, o, 64));
  return v;
}

// ---------------------------------------------------------------------------
// Patch-embed conv
// ---------------------------------------------------------------------------
__global__ __launch_bounds__(256)
void conv_kernel(const float* __restrict__ src, const float* __restrict__ cw,
                 const float* __restrict__ cb, float* __restrict__ X) {
  __shared__ float patch[8][776];
  const int tid = threadIdx.x;
  const int u0 = blockIdx.x * 8;
  for (int j = 0; j < 8; j++) {
    int u = u0 + j;
    int b = u & 7;
    int s = u >> 3;
    int tt = s / WHT;
    int w2 = s % WHT;
    int ph = w2 / 14, pw = w2 % 14;
    const float* sb = src + (size_t)b * (3 * 16 * 224 * 224) +
                      (size_t)tt * (224 * 224) + (size_t)(ph * 16) * 224 + pw * 16;
    for (int e = tid; e < 768; e += 256) {
      int ci = e >> 8;
      int rem = e & 255;
      int py = rem >> 4, px = rem & 15;
      patch[j][e] = sb[(size_t)ci * (16 * 224 * 224) + py * 224 + px];
    }
  }
  __syncthreads();
  float acc0[8] = {0, 0, 0, 0, 0, 0, 0, 0};
  float acc1[8] = {0, 0, 0, 0, 0, 0, 0, 0};
  for (int e0 = 0; e0 < 768; e0 += 4) {
    float4 w0 = *(const float4*)(cw + (size_t)tid * 768 + e0);
    float4 w1 = *(const float4*)(cw + (size_t)(tid + 256) * 768 + e0);
#pragma unroll
    for (int j = 0; j < 8; j++) {
      float4 p = *(const float4*)&patch[j][e0];
      acc0[j] += w0.x * p.x + w0.y * p.y + w0.z * p.z + w0.w * p.w;
      acc1[j] += w1.x * p.x + w1.y * p.y + w1.z * p.z + w1.w * p.w;
    }
  }
  float cb0 = cb[tid], cb1 = cb[tid + 256];
  for (int j = 0; j < 8; j++) {
    int u = u0 + j;
    X[(size_t)(8 + u) * CC + tid] = acc0[j] + cb0;
    X[(size_t)(8 + u) * CC + tid + 256] = acc1[j] + cb1;
  }
}

__global__ void cls_init_kernel(const float* __restrict__ clst, float* __restrict__ X) {
  X[(size_t)blockIdx.x * CC + threadIdx.x] = clst[threadIdx.x];
}

__global__ void copy_cls_kernel(const float* __restrict__ cls, float* __restrict__ A) {
  A[(size_t)blockIdx.x * CC + threadIdx.x] = cls[(size_t)blockIdx.x * CC + threadIdx.x];
}

// ---------------------------------------------------------------------------
// LayerNorm over C=512; one block per row; optional +pos (layer0 q-input)
// ---------------------------------------------------------------------------
__global__ __launch_bounds__(256)
void ln_kernel(const float* __restrict__ X, float* __restrict__ O,
               const float* __restrict__ w, const float* __restrict__ b,
               const float* __restrict__ pos) {
  __shared__ float red[8];
  const int row = blockIdx.x, tid = threadIdx.x;
  const float* x = X + (size_t)row * CC;
  float v0 = x[tid], v1 = x[tid + 256];
  float s = wave_reduce_sum(v0 + v1);
  if ((tid & 63) == 0) red[tid >> 6] = s;
  __syncthreads();
  float mean = (red[0] + red[1] + red[2] + red[3]) * (1.f / 512.f);
  float d0 = v0 - mean, d1 = v1 - mean;
  float vs = wave_reduce_sum(d0 * d0 + d1 * d1);
  if ((tid & 63) == 0) red[4 + (tid >> 6)] = vs;
  __syncthreads();
  float var = (red[4] + red[5] + red[6] + red[7]) * (1.f / 512.f);
  float inv = 1.0f / sqrtf(var + 1e-5f);
  float o0 = d0 * inv * w[tid] + b[tid];
  float o1 = d1 * inv * w[tid + 256] + b[tid + 256];
  if (pos) {
    const float* pr = pos + (size_t)(row >> 3) * CC;
    o0 += pr[tid];
    o1 += pr[tid + 256];
  }
  O[(size_t)row * CC + tid] = o0;
  O[(size_t)row * CC + tid + 256] = o1;
}

// ---------------------------------------------------------------------------
// Generic fp32 GEMM: C = A(M,K) @ W(K,N) + bias  [+relu] [+same-row residual]
// ---------------------------------------------------------------------------
template <int RELU, int RES>
__global__ __launch_bounds__(256)
void gemm_kernel(const float* __restrict__ A, const float* __restrict__ W,
                 const float* __restrict__ bias, float* __restrict__ Cout,
                 int M, int N, int K, const float* __restrict__ resid) {
  __shared__ float As[16][68];
  __shared__ float Wsm[16][68];
  const int tid = threadIdx.x;
  const int tx = tid & 15, ty = tid >> 4;
  const int m0 = blockIdx.x * 64, n0 = blockIdx.y * 64;
  float acc[4][4] = {};
  for (int k0 = 0; k0 < K; k0 += 16) {
    {
      int e = tid * 4;
      int m = e >> 4, kk = e & 15;
      int gm = m0 + m;
      float4 vals;
      if (gm < M)
        vals = *(const float4*)(A + (size_t)gm * K + k0 + kk);
      else
        vals = make_float4(0.f, 0.f, 0.f, 0.f);
      As[kk + 0][m] = vals.x;
      As[kk + 1][m] = vals.y;
      As[kk + 2][m] = vals.z;
      As[kk + 3][m] = vals.w;
    }
    {
      int e = tid * 4;
      int kk = e >> 6, nn = e & 63;
      float4 vals = *(const float4*)(W + (size_t)(k0 + kk) * N + n0 + nn);
      *(float4*)&Wsm[kk][nn] = vals;
    }
    __syncthreads();
#pragma unroll
    for (int kk = 0; kk < 16; kk++) {
      float4 a4 = *(const float4*)&As[kk][ty * 4];
      float4 b4 = *(const float4*)&Wsm[kk][tx * 4];
      float av[4] = {a4.x, a4.y, a4.z, a4.w};
      float bv[4] = {b4.x, b4.y, b4.z, b4.w};
#pragma unroll
      for (int i = 0; i < 4; i++)
#pragma unroll
        for (int j = 0; j < 4; j++) acc[i][j] += av[i] * bv[j];
    }
    __syncthreads();
  }
#pragma unroll
  for (int i = 0; i < 4; i++) {
    int gm = m0 + ty * 4 + i;
    if (gm >= M) continue;
#pragma unroll
    for (int j = 0; j < 4; j++) {
      int gn = n0 + tx * 4 + j;
      float v = acc[i][j] + bias[gn];
      if (RELU) v = fmaxf(v, 0.f);
      if (RES == 1) v += resid[(size_t)gm * N + gn];
      Cout[(size_t)gm * N + gn] = v;
    }
  }
}

// ---------------------------------------------------------------------------
// Class attention
// ---------------------------------------------------------------------------
__global__ __launch_bounds__(256)
void class_attn_kernel(const float* __restrict__ qkv, float* __restrict__ cls, int L) {
  __shared__ float q[64];
  __shared__ float sc[3200];
  __shared__ float red[8];
  __shared__ float pv[256];
  const int h = blockIdx.x & 7, b = blockIdx.x >> 3;
  const int tid = threadIdx.x;
  if (tid < 64) q[tid] = qkv[(size_t)b * 1536 + h * 64 + tid] * 0.125f;
  __syncthreads();
  float lmax = -3.4e38f;
  for (int l = tid; l < L; l += 256) {
    const float* kr = qkv + (size_t)(l * 8 + b) * 1536 + 512 + h * 64;
    float s = 0;
#pragma unroll 8
    for (int d2 = 0; d2 < 64; d2++) s += q[d2] * kr[d2];
    sc[l] = s;
    lmax = fmaxf(lmax, s);
  }
  lmax = wave_reduce_max(lmax);
  if ((tid & 63) == 0) red[tid >> 6] = lmax;
  __syncthreads();
  float gmax = fmaxf(fmaxf(red[0], red[1]), fmaxf(red[2], red[3]));
  float lsum = 0;
  for (int l = tid; l < L; l += 256) {
    float e = expf(sc[l] - gmax);
    sc[l] = e;
    lsum += e;
  }
  lsum = wave_reduce_sum(lsum);
  if ((tid & 63) == 0) red[4 + (tid >> 6)] = lsum;
  __syncthreads();
  float gsum = red[4] + red[5] + red[6] + red[7];
  const int g = tid >> 6, d = tid & 63;
  float acc = 0;
  for (int l = g; l < L; l += 4)
    acc += sc[l] * qkv[(size_t)(l * 8 + b) * 1536 + 1024 + h * 64 + d];
  pv[g * 64 + d] = acc;
  __syncthreads();
  if (g == 0) {
    float tot = pv[d] + pv[64 + d] + pv[128 + d] + pv[192 + d];
    cls[b * CC + h * 64 + d] = tot / gsum;
  }
}

// ---------------------------------------------------------------------------
// Temporal attention + sigma top-k pooling. One block per (h,b,w).
// ---------------------------------------------------------------------------
__global__ __launch_bounds__(256)
void temporal_attn_kernel(const float* __restrict__ qkv, float* __restrict__ Y,
                          int* __restrict__ idxbuf, int t, int tp, int pk) {
  __shared__ float qs[16 * 65], ks[16 * 65], vs[16 * 65];
  __shared__ float a[16 * 17];
  __shared__ float sig[16];
  __shared__ int keepf[16];
  __shared__ int klist[16];
  const int g = blockIdx.x;
  const int w = g % WHT;
  const int bb = (g / WHT) & 7;
  const int h = g / (WHT * 8);
  const int tid = threadIdx.x;
  const int td = t * 64;
  for (int e = tid; e < td; e += 256) {
    int tt = e >> 6, d = e & 63;
    size_t rb = (size_t)((1 + tt * WHT + w) * 8 + bb) * 1536 + h * 64 + d;
    qs[tt * 65 + d] = qkv[rb] * 0.125f;
    ks[tt * 65 + d] = qkv[rb + 512];
    vs[tt * 65 + d] = qkv[rb + 1024];
  }
  __syncthreads();
  if (tid < t * t) {
    int qi = tid / t, ki = tid % t;
    const float* qp = &qs[qi * 65];
    const float* kp = &ks[ki * 65];
    float s = 0;
#pragma unroll 8
    for (int d2 = 0; d2 < 64; d2++) s += qp[d2] * kp[d2];
    a[qi * 17 + ki] = s;
  }
  __syncthreads();
  if (tid < t) {
    float* row = &a[tid * 17];
    float m = row[0];
    for (int k2 = 1; k2 < t; k2++) m = fmaxf(m, row[k2]);
    float sum = 0;
    for (int k2 = 0; k2 < t; k2++) {
      float e2 = expf(row[k2] - m);
      row[k2] = e2;
      sum += e2;
    }
    float inv = 1.f / sum;
    for (int k2 = 0; k2 < t; k2++) row[k2] *= inv;
  }
  __syncthreads();
  if (pk > 0) {
    if (tid < t) {
      const float* row = &a[tid * 17];
      float mean = 0;
      for (int k2 = 0; k2 < t; k2++) mean += row[k2];
      mean /= (float)t;
      float var = 0;
      for (int k2 = 0; k2 < t; k2++) {
        float dl = row[k2] - mean;
        var += dl * dl;
      }
      var /= (float)(t - 1);
      sig[tid] = sqrtf(var);
    }
    __syncthreads();
    if (tid < t) {
      float sv = sig[tid];
      int r = 0;
      for (int q2 = 0; q2 < t; q2++) {
        float so = sig[q2];
        if (so > sv || (so == sv && q2 < tid)) r++;
      }
      keepf[tid] = (r < tp) ? 1 : 0;
    }
    __syncthreads();
    if (tid < t && keepf[tid]) {
      int ppos = 0;
      for (int q2 = 0; q2 < tid; q2++) ppos += keepf[q2];
      klist[ppos] = tid;
      idxbuf[((h * 8 + bb) * WHT + w) * 16 + ppos] = tid;
    }
  } else {
    if (tid < t) klist[tid] = tid;
  }
  __syncthreads();
  const int gq = tid >> 6, d = tid & 63;
  for (int qi = gq; qi < tp; qi += 4) {
    int qq = klist[qi];
    const float* arow = &a[qq * 17];
    float acc = 0;
    for (int k2 = 0; k2 < t; k2++) acc += arow[k2] * vs[k2 * 65 + d];
    Y[(size_t)((qi * WHT + w) * 8 + bb) * CC + h * 64 + d] = acc;
  }
}

// ---------------------------------------------------------------------------
// In-place temporal pooling of the residual stream X.
// ---------------------------------------------------------------------------
__global__ __launch_bounds__(256)
void pool_inplace_kernel(float* __restrict__ X, const int* __restrict__ idxbuf,
                         int tp) {
  const int b = blockIdx.x & 7;
  const int w = blockIdx.x >> 3;
  const int tid = threadIdx.x;
  const int c0 = tid, c1 = tid + 256;
  const int h0 = c0 >> 6, h1 = c1 >> 6;
  const int ib0 = ((h0 * 8 + b) * WHT + w) * 16;
  const int ib1 = ((h1 * 8 + b) * WHT + w) * 16;
  for (int q = 0; q < tp; q++) {
    int s0 = idxbuf[ib0 + q];
    int s1 = idxbuf[ib1 + q];
    size_t drow = (size_t)((1 + q * WHT + w) * 8 + b) * CC;
    if (s0 != q) {
      size_t srow = (size_t)((1 + s0 * WHT + w) * 8 + b) * CC;
      X[drow + c0] = X[srow + c0];
    }
    if (s1 != q) {
      size_t srow = (size_t)((1 + s1 * WHT + w) * 8 + b) * CC;
      X[drow + c1] = X[srow + c1];
    }
  }
}

// ---------------------------------------------------------------------------
// Spatial attention v3: one block per (h,b,t); 13 q-tiles of 16 in-block.
// Register-bounded inner loops (no spills): score phase = 4 acc/thread with
// float4 LDS reads (#pragma unroll 2); PV phase = 4 acc/thread, S broadcast
// via float4. LDS strides 68 floats (16B-aligned, <=2-way bank conflicts).
// ---------------------------------------------------------------------------
__global__ __launch_bounds__(256)
void spatial_attn3_kernel(const float* __restrict__ qkv, float* __restrict__ outA) {
  __shared__ float Qs[16 * 68];
  __shared__ float Ks[64 * 68];
  __shared__ float Vs[64 * 68];
  __shared__ float S[16 * 200];
  const int blk = blockIdx.x;
  const int h = blk & 7;
  const int b = (blk >> 3) & 7;
  const int tq = blk >> 6;
  const int tid = threadIdx.x;
  const size_t base = (size_t)((size_t)tq * WHT * 8 + b) * 1536 + h * 64;

  const int i16 = tid >> 4;  // q-row for score phase
  const int jj = tid & 15;   // key sub-index for score phase
  const int qg = tid >> 6;   // q-row group for PV phase
  const int d = tid & 63;    // head-dim column for PV phase

  for (int qt = 0; qt < 13; qt++) {
    __syncthreads();  // all reads of Qs/S/Vs from previous tile done
    // ---- load Q tile (16 x 64), one float4 per thread, scaled ----
    {
      int i = tid >> 4, f4 = (tid & 15) * 4;
      int w = qt * 16 + i;
      float4 v = make_float4(0.f, 0.f, 0.f, 0.f);
      if (w < WHT) {
        v = *(const float4*)(qkv + base + (size_t)w * 12288 + f4);
        v.x *= 0.125f; v.y *= 0.125f; v.z *= 0.125f; v.w *= 0.125f;
      }
      *(float4*)&Qs[i * 68 + f4] = v;
    }
    // ---- scores: 4 chunks of 64 keys ----
    for (int kc = 0; kc < WHT; kc += 64) {
      const int cn = min(64, WHT - kc);
      __syncthreads();  // Qs visible (first it.) / prev chunk compute done
#pragma unroll
      for (int r = 0; r < 4; r++) {
        int e = tid + r * 256;
        int j = e >> 4, f4 = (e & 15) * 4;
        int krow = kc + j;
        float4 v = make_float4(0.f, 0.f, 0.f, 0.f);
        if (krow < WHT)
          v = *(const float4*)(qkv + base + (size_t)krow * 12288 + 512 + f4);
        *(float4*)&Ks[j * 68 + f4] = v;
      }
      __syncthreads();
      float s0 = 0.f, s1 = 0.f, s2 = 0.f, s3 = 0.f;
      const float* qrow = &Qs[i16 * 68];
      const float* k0 = &Ks[jj * 68];
      const float* k1 = &Ks[(jj + 16) * 68];
      const float* k2 = &Ks[(jj + 32) * 68];
      const float* k3 = &Ks[(jj + 48) * 68];
#pragma unroll 2
      for (int d2 = 0; d2 < 64; d2 += 4) {
        float4 q4 = *(const float4*)(qrow + d2);
        float4 a0 = *(const float4*)(k0 + d2);
        float4 a1 = *(const float4*)(k1 + d2);
        float4 a2 = *(const float4*)(k2 + d2);
        float4 a3 = *(const float4*)(k3 + d2);
        s0 += q4.x * a0.x + q4.y * a0.y + q4.z * a0.z + q4.w * a0.w;
        s1 += q4.x * a1.x + q4.y * a1.y + q4.z * a1.z + q4.w * a1.w;
        s2 += q4.x * a2.x + q4.y * a2.y + q4.z * a2.z + q4.w * a2.w;
        s3 += q4.x * a3.x + q4.y * a3.y + q4.z * a3.z + q4.w * a3.w;
      }
      float* srow = &S[i16 * 200 + kc];
      if (jj < cn) srow[jj] = s0;
      if (jj + 16 < cn) srow[jj + 16] = s1;
      if (jj + 32 < cn) srow[jj + 32] = s2;
      if (jj + 48 < cn) srow[jj + 48] = s3;
    }
    __syncthreads();
    // ---- parallel softmax: 16 lanes per row ----
    {
      const int row = tid >> 4;
      const int lane = tid & 15;
      float* srow = &S[row * 200];
      float m = -3.4e38f;
      for (int j = lane; j < WHT; j += 16) m = fmaxf(m, srow[j]);
#pragma unroll
      for (int msk = 8; msk >= 1; msk >>= 1) m = fmaxf(m, __shfl_xor(m, msk, 16));
      float l = 0.f;
      for (int j = lane; j < WHT; j += 16) {
        float e = expf(srow[j] - m);
        srow[j] = e;
        l += e;
      }
#pragma unroll
      for (int msk = 8; msk >= 1; msk >>= 1) l += __shfl_xor(l, msk, 16);
      float inv = 1.f / l;
      for (int j = lane; j < WHT; j += 16) srow[j] *= inv;
    }
    // ---- PV: thread owns rows {qg,qg+4,qg+8,qg+12} at column d ----
    float acc[4] = {0.f, 0.f, 0.f, 0.f};
    for (int vc = 0; vc < WHT; vc += 64) {
      const int cn = min(64, WHT - vc);
      __syncthreads();  // softmax S visible (first it.) / prev Vs reads done
#pragma unroll
      for (int r = 0; r < 4; r++) {
        int e = tid + r * 256;
        int j = e >> 4, f4 = (e & 15) * 4;
        int vrow = vc + j;
        float4 v = make_float4(0.f, 0.f, 0.f, 0.f);
        if (vrow < WHT)
          v = *(const float4*)(qkv + base + (size_t)vrow * 12288 + 1024 + f4);
        *(float4*)&Vs[j * 68 + f4] = v;
      }
      __syncthreads();
#pragma unroll 2
      for (int j4 = 0; j4 < cn; j4 += 4) {
        float v0 = Vs[(j4 + 0) * 68 + d];
        float v1 = Vs[(j4 + 1) * 68 + d];
        float v2 = Vs[(j4 + 2) * 68 + d];
        float v3 = Vs[(j4 + 3) * 68 + d];
#pragma unroll
        for (int u = 0; u < 4; u++) {
          float4 s4 = *(const float4*)&S[(qg + 4 * u) * 200 + vc + j4];
          acc[u] += s4.x * v0 + s4.y * v1 + s4.z * v2 + s4.w * v3;
        }
      }
    }
    // ---- store O tile ----
#pragma unroll
    for (int u = 0; u < 4; u++) {
      int i = qg + 4 * u;
      int w = qt * 16 + i;
      if (w < WHT)
        outA[(size_t)((1 + tq * WHT + w) * 8 + b) * CC + h * 64 + d] = acc[u];
    }
  }
}

// ---------------------------------------------------------------------------
// Final LN (token 0 only) + classifier head
// ---------------------------------------------------------------------------
__global__ __launch_bounds__(256)
void head_kernel(const float* __restrict__ X, const float* __restrict__ enw,
                 const float* __restrict__ enb, const float* __restrict__ fcw,
                 const float* __restrict__ fcb, float* __restrict__ out) {
  __shared__ float nx[512];
  __shared__ float red[8];
  const int b = blockIdx.x, tid = threadIdx.x;
  const float* x = X + (size_t)b * CC;
  float v0 = x[tid], v1 = x[tid + 256];
  float s = wave_reduce_sum(v0 + v1);
  if ((tid & 63) == 0) red[tid >> 6] = s;
  __syncthreads();
  float mean = (red[0] + red[1] + red[2] + red[3]) * (1.f / 512.f);
  float d0 = v0 - mean, d1 = v1 - mean;
  float vs = wave_reduce_sum(d0 * d0 + d1 * d1);
  if ((tid & 63) == 0) red[4 + (tid >> 6)] = vs;
  __syncthreads();
  float var = (red[4] + red[5] + red[6] + red[7]) * (1.f / 512.f);
  float inv = 1.0f / sqrtf(var + 1e-5f);
  nx[tid] = d0 * inv * enw[tid] + enb[tid];
  nx[tid + 256] = d1 * inv * enw[tid + 256] + enb[tid + 256];
  __syncthreads();
  if (tid < NCLS) {
    float acc = fcb[tid];
    for (int c = 0; c < 512; c++) acc += nx[c] * fcw[c * NCLS + tid];
    out[b * NCLS + tid] = acc;
  }
}

// ---------------------------------------------------------------------------
extern "C" void kernel_launch(void* const* d_in, const int* in_sizes, int n_in,
                              void* d_out, int out_size, void* d_ws, size_t ws_size,
                              hipStream_t stream) {
  (void)in_sizes; (void)n_in; (void)out_size; (void)ws_size;
  const float* src  = (const float*)d_in[0];
  const float* cw   = (const float*)d_in[1];
  const float* cb   = (const float*)d_in[2];
  const float* clst = (const float*)d_in[3];
  const float* pos  = (const float*)d_in[4];
  const float* Wt   = (const float*)d_in[5];
  const float* bt   = (const float*)d_in[6];
  const float* Wsp  = (const float*)d_in[7];
  const float* bsp  = (const float*)d_in[8];
  const float* Wo   = (const float*)d_in[9];
  const float* bo   = (const float*)d_in[10];
  const float* n1w  = (const float*)d_in[11];
  const float* n1b  = (const float*)d_in[12];
  const float* n2w  = (const float*)d_in[13];
  const float* n2b  = (const float*)d_in[14];
  const float* W1   = (const float*)d_in[15];
  const float* b1   = (const float*)d_in[16];
  const float* W2   = (const float*)d_in[17];
  const float* b2   = (const float*)d_in[18];
  const float* enw  = (const float*)d_in[19];
  const float* enb  = (const float*)d_in[20];
  const float* fcw  = (const float*)d_in[21];
  const float* fcb  = (const float*)d_in[22];

  float* ws = (float*)d_ws;
  const size_t TOKR = (size_t)3137 * 8;
  float* X0  = ws;                        // TOKR*512
  float* Ab  = X0 + TOKR * 512;           // TOKR*512
  float* QKV = Ab + TOKR * 512;           // TOKR*1536 (also FFN-mid chunks)
  float* CLS = QKV + TOKR * 1536;         // 8*512
  int*   IDX = (int*)(CLS + 8 * 512);     // 8*8*196*16 ints

  conv_kernel<<<3136, 256, 0, stream>>>(src, cw, cb, X0);
  cls_init_kernel<<<8, 512, 0, stream>>>(clst, X0);

  float* Xc = X0;
  int t = 16;
  const int FFN_CHUNK = 16384;
  for (int i = 0; i < 6; i++) {
    const int pk = (i & 1) ? 2 : 0;
    const int tp = t - pk;
    const int L = 1 + t * WHT;
    const int Lo = 1 + tp * WHT;
    const int M = L * 8, Mo = Lo * 8, My = tp * WHT * 8;

    ln_kernel<<<M, 256, 0, stream>>>(Xc, Ab, n1w + (size_t)i * 512, n1b + (size_t)i * 512,
                                     (i == 0) ? pos : nullptr);
    gemm_kernel<0, 0><<<dim3((M + 63) / 64, 24), 256, 0, stream>>>(
        Ab, Wt + (size_t)i * 512 * 1536, bt + (size_t)i * 1536, QKV, M, 1536, 512,
        nullptr);
    class_attn_kernel<<<64, 256, 0, stream>>>(QKV, CLS, L);
    temporal_attn_kernel<<<HH * BB * WHT, 256, 0, stream>>>(QKV, Ab, IDX, t, tp, pk);
    gemm_kernel<0, 0><<<dim3((My + 63) / 64, 24), 256, 0, stream>>>(
        Ab, Wsp + (size_t)i * 512 * 1536, bsp + (size_t)i * 1536, QKV, My, 1536, 512,
        nullptr);
    copy_cls_kernel<<<8, 512, 0, stream>>>(CLS, Ab);
    spatial_attn3_kernel<<<64 * t, 256, 0, stream>>>(QKV, Ab);
    if (pk > 0)
      pool_inplace_kernel<<<8 * WHT, 256, 0, stream>>>(Xc, IDX, tp);
    gemm_kernel<0, 1><<<dim3((Mo + 63) / 64, 8), 256, 0, stream>>>(
        Ab, Wo + (size_t)i * 512 * 512, bo + (size_t)i * 512, Xc, Mo, 512, 512, Xc);
    ln_kernel<<<Mo, 256, 0, stream>>>(Xc, Ab, n2w + (size_t)i * 512, n2b + (size_t)i * 512,
                                      nullptr);
    for (int off = 0; off < Mo; off += FFN_CHUNK) {
      int R = Mo - off;
      if (R > FFN_CHUNK) R = FFN_CHUNK;
      gemm_kernel<1, 0><<<dim3((R + 63) / 64, 32), 256, 0, stream>>>(
          Ab + (size_t)off * 512, W1 + (size_t)i * 512 * 2048, b1 + (size_t)i * 2048,
          QKV, R, 2048, 512, nullptr);
      gemm_kernel<0, 1><<<dim3((R + 63) / 64, 8), 256, 0, stream>>>(
          QKV, W2 + (size_t)i * 2048 * 512, b2 + (size_t)i * 512,
          Xc + (size_t)off * 512, R, 512, 2048, Xc + (size_t)off * 512);
    }
    t = tp;
  }
  head_kernel<<<8, 256, 0, stream>>>(Xc, enw, enb, fcw, fcb, (float*)d_out);
}

// Round 5
// 11759.100 us; speedup vs baseline: 4.5875x; 1.6599x over previous
//
#include <hip/hip_runtime.h>
#include <math.h>

// ---------------------------------------------------------------------------
// CompactVidTr forward. fp32 everywhere except Ws/Wo/FFN GEMMs (bf16 MFMA).
// The sigma-top-k path (Wt GEMM -> temporal attention ranking) stays fp32:
// a bf16-induced rank flip would be an O(1) output error.
// Layout: token matrices row-major [row = l*B + b][C]; l=0 is cls. B=8, C=512.
//
// Workspace (261.9 MB < 256 MiB=268.4 MB):
//   X   : 3137*8 x 512  fp32   (51.4 MB)  residual stream, pooled IN PLACE
//   Ab  : 3137*8 x 512  fp32   (51.4 MB)  LN out / attention out staging
//   QKV : 3137*8 x 1536 fp32  (154.1 MB)  qkv GEMM out; reused as FFN mid
//   CLS : 8x512 fp32, IDX: 8*8*196*16 int (~0.8 MB)
//   WT1 : 2048*512 bf16 (2.1 MB)  transposed weight scratch (Ws/Wo/W1)
//   WT2 : 2048*512 bf16 (2.1 MB)  transposed weight scratch (W2)
// ---------------------------------------------------------------------------

#define BB 8
#define CC 512
#define HH 8
#define HD 64
#define WHT 196
#define NCLS 157

typedef short bf16x8 __attribute__((ext_vector_type(8)));
typedef float floatx4 __attribute__((ext_vector_type(4)));

__device__ __forceinline__ unsigned short f2bf(float f) {
  unsigned u = __float_as_uint(f);
  unsigned r = u + 0x7FFFu + ((u >> 16) & 1u);  // RNE
  return (unsigned short)(r >> 16);
}

__device__ __forceinline__ float wave_reduce_sum(float v) {
#pragma unroll
  for (int o = 32; o > 0; o >>= 1) v += __shfl_down(v, o, 64);
  return v;
}
__device__ __forceinline__ float wave_reduce_max(float v) {
#pragma unroll
  for (int o = 32; o > 0; o >>= 1) v = fmaxf(v, __shfl_down(v, o, 64));
  return v;
}

// ---------------------------------------------------------------------------
// Patch-embed conv
// ---------------------------------------------------------------------------
__global__ __launch_bounds__(256)
void conv_kernel(const float* __restrict__ src, const float* __restrict__ cw,
                 const float* __restrict__ cb, float* __restrict__ X) {
  __shared__ float patch[8][776];
  const int tid = threadIdx.x;
  const int u0 = blockIdx.x * 8;
  for (int j = 0; j < 8; j++) {
    int u = u0 + j;
    int b = u & 7;
    int s = u >> 3;
    int tt = s / WHT;
    int w2 = s % WHT;
    int ph = w2 / 14, pw = w2 % 14;
    const float* sb = src + (size_t)b * (3 * 16 * 224 * 224) +
                      (size_t)tt * (224 * 224) + (size_t)(ph * 16) * 224 + pw * 16;
    for (int e = tid; e < 768; e += 256) {
      int ci = e >> 8;
      int rem = e & 255;
      int py = rem >> 4, px = rem & 15;
      patch[j][e] = sb[(size_t)ci * (16 * 224 * 224) + py * 224 + px];
    }
  }
  __syncthreads();
  float acc0[8] = {0, 0, 0, 0, 0, 0, 0, 0};
  float acc1[8] = {0, 0, 0, 0, 0, 0, 0, 0};
  for (int e0 = 0; e0 < 768; e0 += 4) {
    float4 w0 = *(const float4*)(cw + (size_t)tid * 768 + e0);
    float4 w1 = *(const float4*)(cw + (size_t)(tid + 256) * 768 + e0);
#pragma unroll
    for (int j = 0; j < 8; j++) {
      float4 p = *(const float4*)&patch[j][e0];
      acc0[j] += w0.x * p.x + w0.y * p.y + w0.z * p.z + w0.w * p.w;
      acc1[j] += w1.x * p.x + w1.y * p.y + w1.z * p.z + w1.w * p.w;
    }
  }
  float cb0 = cb[tid], cb1 = cb[tid + 256];
  for (int j = 0; j < 8; j++) {
    int u = u0 + j;
    X[(size_t)(8 + u) * CC + tid] = acc0[j] + cb0;
    X[(size_t)(8 + u) * CC + tid + 256] = acc1[j] + cb1;
  }
}

__global__ void cls_init_kernel(const float* __restrict__ clst, float* __restrict__ X) {
  X[(size_t)blockIdx.x * CC + threadIdx.x] = clst[threadIdx.x];
}

__global__ void copy_cls_kernel(const float* __restrict__ cls, float* __restrict__ A) {
  A[(size_t)blockIdx.x * CC + threadIdx.x] = cls[(size_t)blockIdx.x * CC + threadIdx.x];
}

// ---------------------------------------------------------------------------
// LayerNorm over C=512; one block per row; optional +pos (layer0 q-input)
// ---------------------------------------------------------------------------
__global__ __launch_bounds__(256)
void ln_kernel(const float* __restrict__ X, float* __restrict__ O,
               const float* __restrict__ w, const float* __restrict__ b,
               const float* __restrict__ pos) {
  __shared__ float red[8];
  const int row = blockIdx.x, tid = threadIdx.x;
  const float* x = X + (size_t)row * CC;
  float v0 = x[tid], v1 = x[tid + 256];
  float s = wave_reduce_sum(v0 + v1);
  if ((tid & 63) == 0) red[tid >> 6] = s;
  __syncthreads();
  float mean = (red[0] + red[1] + red[2] + red[3]) * (1.f / 512.f);
  float d0 = v0 - mean, d1 = v1 - mean;
  float vs = wave_reduce_sum(d0 * d0 + d1 * d1);
  if ((tid & 63) == 0) red[4 + (tid >> 6)] = vs;
  __syncthreads();
  float var = (red[4] + red[5] + red[6] + red[7]) * (1.f / 512.f);
  float inv = 1.0f / sqrtf(var + 1e-5f);
  float o0 = d0 * inv * w[tid] + b[tid];
  float o1 = d1 * inv * w[tid + 256] + b[tid + 256];
  if (pos) {
    const float* pr = pos + (size_t)(row >> 3) * CC;
    o0 += pr[tid];
    o1 += pr[tid + 256];
  }
  O[(size_t)row * CC + tid] = o0;
  O[(size_t)row * CC + tid + 256] = o1;
}

// ---------------------------------------------------------------------------
// fp32 GEMM (kept for the sigma-critical Wt path only)
// ---------------------------------------------------------------------------
template <int RELU, int RES>
__global__ __launch_bounds__(256)
void gemm_kernel(const float* __restrict__ A, const float* __restrict__ W,
                 const float* __restrict__ bias, float* __restrict__ Cout,
                 int M, int N, int K, const float* __restrict__ resid) {
  __shared__ float As[16][68];
  __shared__ float Wsm[16][68];
  const int tid = threadIdx.x;
  const int tx = tid & 15, ty = tid >> 4;
  const int m0 = blockIdx.x * 64, n0 = blockIdx.y * 64;
  float acc[4][4] = {};
  for (int k0 = 0; k0 < K; k0 += 16) {
    {
      int e = tid * 4;
      int m = e >> 4, kk = e & 15;
      int gm = m0 + m;
      float4 vals;
      if (gm < M)
        vals = *(const float4*)(A + (size_t)gm * K + k0 + kk);
      else
        vals = make_float4(0.f, 0.f, 0.f, 0.f);
      As[kk + 0][m] = vals.x;
      As[kk + 1][m] = vals.y;
      As[kk + 2][m] = vals.z;
      As[kk + 3][m] = vals.w;
    }
    {
      int e = tid * 4;
      int kk = e >> 6, nn = e & 63;
      float4 vals = *(const float4*)(W + (size_t)(k0 + kk) * N + n0 + nn);
      *(float4*)&Wsm[kk][nn] = vals;
    }
    __syncthreads();
#pragma unroll
    for (int kk = 0; kk < 16; kk++) {
      float4 a4 = *(const float4*)&As[kk][ty * 4];
      float4 b4 = *(const float4*)&Wsm[kk][tx * 4];
      float av[4] = {a4.x, a4.y, a4.z, a4.w};
      float bv[4] = {b4.x, b4.y, b4.z, b4.w};
#pragma unroll
      for (int i = 0; i < 4; i++)
#pragma unroll
        for (int j = 0; j < 4; j++) acc[i][j] += av[i] * bv[j];
    }
    __syncthreads();
  }
#pragma unroll
  for (int i = 0; i < 4; i++) {
    int gm = m0 + ty * 4 + i;
    if (gm >= M) continue;
#pragma unroll
    for (int j = 0; j < 4; j++) {
      int gn = n0 + tx * 4 + j;
      float v = acc[i][j] + bias[gn];
      if (RELU) v = fmaxf(v, 0.f);
      if (RES == 1) v += resid[(size_t)gm * N + gn];
      Cout[(size_t)gm * N + gn] = v;
    }
  }
}

// ---------------------------------------------------------------------------
// Weight transpose + fp32->bf16: W [K][N] -> WT [N][K].  grid (N/32, K/32).
// ---------------------------------------------------------------------------
__global__ __launch_bounds__(256)
void wtrans_kernel(const float* __restrict__ W, unsigned short* __restrict__ WT,
                   int N, int K) {
  __shared__ float tile[32][33];
  const int tid = threadIdx.x;
  const int tx = tid & 31, ty = tid >> 5;  // ty 0..7
  const int n0 = blockIdx.x * 32, k0 = blockIdx.y * 32;
#pragma unroll
  for (int r = 0; r < 4; r++) {
    int kk = ty + r * 8;
    tile[kk][tx] = W[(size_t)(k0 + kk) * N + n0 + tx];
  }
  __syncthreads();
#pragma unroll
  for (int r = 0; r < 4; r++) {
    int nn = ty + r * 8;
    WT[(size_t)(n0 + nn) * K + k0 + tx] = f2bf(tile[tx][nn]);
  }
}

// ---------------------------------------------------------------------------
// bf16 MFMA GEMM: C = A(M,K) @ W(K,N) + bias [+relu] [+same-row residual]
// A fp32 (converted in staging), WT = bf16 [N][K] (pre-transposed).
// 128x128 tile, 256 thr = 4 waves; each wave 64x64 via 4x4 mfma 16x16x32.
// LDS stride 40 bf16 (80 B) -> all ds_read_b128 16B-aligned. fp32 out.
// ---------------------------------------------------------------------------
template <int RELU, int RES>
__global__ __launch_bounds__(256)
void mfma_gemm_kernel(const float* __restrict__ A,
                      const unsigned short* __restrict__ WT,
                      const float* __restrict__ bias, float* __restrict__ Cout,
                      int M, int N, int K, const float* __restrict__ resid) {
  __shared__ unsigned short AsU[128 * 40];
  __shared__ unsigned short BsU[128 * 40];
  const int tid = threadIdx.x;
  const int wave = tid >> 6, lane = tid & 63;
  const int quad = lane >> 4, l16 = lane & 15;
  const int wrow = (wave >> 1) * 64, wcol = (wave & 1) * 64;
  const int m0 = blockIdx.x * 128, n0 = blockIdx.y * 128;

  floatx4 acc[4][4];
#pragma unroll
  for (int i = 0; i < 4; i++)
#pragma unroll
    for (int j = 0; j < 4; j++) acc[i][j] = (floatx4){0.f, 0.f, 0.f, 0.f};

  for (int k0 = 0; k0 < K; k0 += 32) {
    // stage A (128 x 32 fp32 -> bf16)
#pragma unroll
    for (int r = 0; r < 4; r++) {
      int e = (tid + r * 256) * 4;
      int row = e >> 5, col = e & 31;
      int gm = m0 + row;
      float4 v = make_float4(0.f, 0.f, 0.f, 0.f);
      if (gm < M) v = *(const float4*)(A + (size_t)gm * K + k0 + col);
      ushort4 o;
      o.x = f2bf(v.x); o.y = f2bf(v.y); o.z = f2bf(v.z); o.w = f2bf(v.w);
      *(ushort4*)&AsU[row * 40 + col] = o;
    }
    // stage B from WT [N][K] (bf16, k-contiguous)
#pragma unroll
    for (int r = 0; r < 4; r++) {
      int e = (tid + r * 256) * 4;
      int n = e >> 5, k = e & 31;
      ushort4 w = *(const ushort4*)(WT + (size_t)(n0 + n) * K + k0 + k);
      *(ushort4*)&BsU[n * 40 + k] = w;
    }
    __syncthreads();
    bf16x8 af[4], bf[4];
#pragma unroll
    for (int i = 0; i < 4; i++)
      af[i] = *(const bf16x8*)&AsU[(wrow + i * 16 + l16) * 40 + quad * 8];
#pragma unroll
    for (int j = 0; j < 4; j++)
      bf[j] = *(const bf16x8*)&BsU[(wcol + j * 16 + l16) * 40 + quad * 8];
#pragma unroll
    for (int i = 0; i < 4; i++)
#pragma unroll
      for (int j = 0; j < 4; j++)
        acc[i][j] = __builtin_amdgcn_mfma_f32_16x16x32_bf16(af[i], bf[j],
                                                            acc[i][j], 0, 0, 0);
    __syncthreads();
  }
  // epilogue: D row = quad*4+reg, col = l16 within each 16x16 tile
#pragma unroll
  for (int i = 0; i < 4; i++) {
#pragma unroll
    for (int p = 0; p < 4; p++) {
      int gm = m0 + wrow + i * 16 + quad * 4 + p;
      if (gm >= M) continue;
#pragma unroll
      for (int j = 0; j < 4; j++) {
        int gn = n0 + wcol + j * 16 + l16;
        float v = acc[i][j][p] + bias[gn];
        if (RELU) v = fmaxf(v, 0.f);
        if (RES == 1) v += resid[(size_t)gm * N + gn];
        Cout[(size_t)gm * N + gn] = v;
      }
    }
  }
}

// ---------------------------------------------------------------------------
// Class attention
// ---------------------------------------------------------------------------
__global__ __launch_bounds__(256)
void class_attn_kernel(const float* __restrict__ qkv, float* __restrict__ cls, int L) {
  __shared__ float q[64];
  __shared__ float sc[3200];
  __shared__ float red[8];
  __shared__ float pv[256];
  const int h = blockIdx.x & 7, b = blockIdx.x >> 3;
  const int tid = threadIdx.x;
  if (tid < 64) q[tid] = qkv[(size_t)b * 1536 + h * 64 + tid] * 0.125f;
  __syncthreads();
  float lmax = -3.4e38f;
  for (int l = tid; l < L; l += 256) {
    const float* kr = qkv + (size_t)(l * 8 + b) * 1536 + 512 + h * 64;
    float s = 0;
#pragma unroll 8
    for (int d2 = 0; d2 < 64; d2++) s += q[d2] * kr[d2];
    sc[l] = s;
    lmax = fmaxf(lmax, s);
  }
  lmax = wave_reduce_max(lmax);
  if ((tid & 63) == 0) red[tid >> 6] = lmax;
  __syncthreads();
  float gmax = fmaxf(fmaxf(red[0], red[1]), fmaxf(red[2], red[3]));
  float lsum = 0;
  for (int l = tid; l < L; l += 256) {
    float e = expf(sc[l] - gmax);
    sc[l] = e;
    lsum += e;
  }
  lsum = wave_reduce_sum(lsum);
  if ((tid & 63) == 0) red[4 + (tid >> 6)] = lsum;
  __syncthreads();
  float gsum = red[4] + red[5] + red[6] + red[7];
  const int g = tid >> 6, d = tid & 63;
  float acc = 0;
  for (int l = g; l < L; l += 4)
    acc += sc[l] * qkv[(size_t)(l * 8 + b) * 1536 + 1024 + h * 64 + d];
  pv[g * 64 + d] = acc;
  __syncthreads();
  if (g == 0) {
    float tot = pv[d] + pv[64 + d] + pv[128 + d] + pv[192 + d];
    cls[b * CC + h * 64 + d] = tot / gsum;
  }
}

// ---------------------------------------------------------------------------
// Temporal attention + sigma top-k pooling (fp32 — rank-critical).
// ---------------------------------------------------------------------------
__global__ __launch_bounds__(256)
void temporal_attn_kernel(const float* __restrict__ qkv, float* __restrict__ Y,
                          int* __restrict__ idxbuf, int t, int tp, int pk) {
  __shared__ float qs[16 * 65], ks[16 * 65], vs[16 * 65];
  __shared__ float a[16 * 17];
  __shared__ float sig[16];
  __shared__ int keepf[16];
  __shared__ int klist[16];
  const int g = blockIdx.x;
  const int w = g % WHT;
  const int bb = (g / WHT) & 7;
  const int h = g / (WHT * 8);
  const int tid = threadIdx.x;
  const int td = t * 64;
  for (int e = tid; e < td; e += 256) {
    int tt = e >> 6, d = e & 63;
    size_t rb = (size_t)((1 + tt * WHT + w) * 8 + bb) * 1536 + h * 64 + d;
    qs[tt * 65 + d] = qkv[rb] * 0.125f;
    ks[tt * 65 + d] = qkv[rb + 512];
    vs[tt * 65 + d] = qkv[rb + 1024];
  }
  __syncthreads();
  if (tid < t * t) {
    int qi = tid / t, ki = tid % t;
    const float* qp = &qs[qi * 65];
    const float* kp = &ks[ki * 65];
    float s = 0;
#pragma unroll 8
    for (int d2 = 0; d2 < 64; d2++) s += qp[d2] * kp[d2];
    a[qi * 17 + ki] = s;
  }
  __syncthreads();
  if (tid < t) {
    float* row = &a[tid * 17];
    float m = row[0];
    for (int k2 = 1; k2 < t; k2++) m = fmaxf(m, row[k2]);
    float sum = 0;
    for (int k2 = 0; k2 < t; k2++) {
      float e2 = expf(row[k2] - m);
      row[k2] = e2;
      sum += e2;
    }
    float inv = 1.f / sum;
    for (int k2 = 0; k2 < t; k2++) row[k2] *= inv;
  }
  __syncthreads();
  if (pk > 0) {
    if (tid < t) {
      const float* row = &a[tid * 17];
      float mean = 0;
      for (int k2 = 0; k2 < t; k2++) mean += row[k2];
      mean /= (float)t;
      float var = 0;
      for (int k2 = 0; k2 < t; k2++) {
        float dl = row[k2] - mean;
        var += dl * dl;
      }
      var /= (float)(t - 1);
      sig[tid] = sqrtf(var);
    }
    __syncthreads();
    if (tid < t) {
      float sv = sig[tid];
      int r = 0;
      for (int q2 = 0; q2 < t; q2++) {
        float so = sig[q2];
        if (so > sv || (so == sv && q2 < tid)) r++;
      }
      keepf[tid] = (r < tp) ? 1 : 0;
    }
    __syncthreads();
    if (tid < t && keepf[tid]) {
      int ppos = 0;
      for (int q2 = 0; q2 < tid; q2++) ppos += keepf[q2];
      klist[ppos] = tid;
      idxbuf[((h * 8 + bb) * WHT + w) * 16 + ppos] = tid;
    }
  } else {
    if (tid < t) klist[tid] = tid;
  }
  __syncthreads();
  const int gq = tid >> 6, d = tid & 63;
  for (int qi = gq; qi < tp; qi += 4) {
    int qq = klist[qi];
    const float* arow = &a[qq * 17];
    float acc = 0;
    for (int k2 = 0; k2 < t; k2++) acc += arow[k2] * vs[k2 * 65 + d];
    Y[(size_t)((qi * WHT + w) * 8 + bb) * CC + h * 64 + d] = acc;
  }
}

// ---------------------------------------------------------------------------
// In-place temporal pooling of the residual stream X.
// ---------------------------------------------------------------------------
__global__ __launch_bounds__(256)
void pool_inplace_kernel(float* __restrict__ X, const int* __restrict__ idxbuf,
                         int tp) {
  const int b = blockIdx.x & 7;
  const int w = blockIdx.x >> 3;
  const int tid = threadIdx.x;
  const int c0 = tid, c1 = tid + 256;
  const int h0 = c0 >> 6, h1 = c1 >> 6;
  const int ib0 = ((h0 * 8 + b) * WHT + w) * 16;
  const int ib1 = ((h1 * 8 + b) * WHT + w) * 16;
  for (int q = 0; q < tp; q++) {
    int s0 = idxbuf[ib0 + q];
    int s1 = idxbuf[ib1 + q];
    size_t drow = (size_t)((1 + q * WHT + w) * 8 + b) * CC;
    if (s0 != q) {
      size_t srow = (size_t)((1 + s0 * WHT + w) * 8 + b) * CC;
      X[drow + c0] = X[srow + c0];
    }
    if (s1 != q) {
      size_t srow = (size_t)((1 + s1 * WHT + w) * 8 + b) * CC;
      X[drow + c1] = X[srow + c1];
    }
  }
}

// ---------------------------------------------------------------------------
// Spatial attention v3 (register-bounded, round-4 version)
// ---------------------------------------------------------------------------
__global__ __launch_bounds__(256)
void spatial_attn3_kernel(const float* __restrict__ qkv, float* __restrict__ outA) {
  __shared__ float Qs[16 * 68];
  __shared__ float Ks[64 * 68];
  __shared__ float Vs[64 * 68];
  __shared__ float S[16 * 200];
  const int blk = blockIdx.x;
  const int h = blk & 7;
  const int b = (blk >> 3) & 7;
  const int tq = blk >> 6;
  const int tid = threadIdx.x;
  const size_t base = (size_t)((size_t)tq * WHT * 8 + b) * 1536 + h * 64;

  const int i16 = tid >> 4;
  const int jj = tid & 15;
  const int qg = tid >> 6;
  const int d = tid & 63;

  for (int qt = 0; qt < 13; qt++) {
    __syncthreads();
    {
      int i = tid >> 4, f4 = (tid & 15) * 4;
      int w = qt * 16 + i;
      float4 v = make_float4(0.f, 0.f, 0.f, 0.f);
      if (w < WHT) {
        v = *(const float4*)(qkv + base + (size_t)w * 12288 + f4);
        v.x *= 0.125f; v.y *= 0.125f; v.z *= 0.125f; v.w *= 0.125f;
      }
      *(float4*)&Qs[i * 68 + f4] = v;
    }
    for (int kc = 0; kc < WHT; kc += 64) {
      const int cn = min(64, WHT - kc);
      __syncthreads();
#pragma unroll
      for (int r = 0; r < 4; r++) {
        int e = tid + r * 256;
        int j = e >> 4, f4 = (e & 15) * 4;
        int krow = kc + j;
        float4 v = make_float4(0.f, 0.f, 0.f, 0.f);
        if (krow < WHT)
          v = *(const float4*)(qkv + base + (size_t)krow * 12288 + 512 + f4);
        *(float4*)&Ks[j * 68 + f4] = v;
      }
      __syncthreads();
      float s0 = 0.f, s1 = 0.f, s2 = 0.f, s3 = 0.f;
      const float* qrow = &Qs[i16 * 68];
      const float* k0 = &Ks[jj * 68];
      const float* k1 = &Ks[(jj + 16) * 68];
      const float* k2 = &Ks[(jj + 32) * 68];
      const float* k3 = &Ks[(jj + 48) * 68];
#pragma unroll 2
      for (int d2 = 0; d2 < 64; d2 += 4) {
        float4 q4 = *(const float4*)(qrow + d2);
        float4 a0 = *(const float4*)(k0 + d2);
        float4 a1 = *(const float4*)(k1 + d2);
        float4 a2 = *(const float4*)(k2 + d2);
        float4 a3 = *(const float4*)(k3 + d2);
        s0 += q4.x * a0.x + q4.y * a0.y + q4.z * a0.z + q4.w * a0.w;
        s1 += q4.x * a1.x + q4.y * a1.y + q4.z * a1.z + q4.w * a1.w;
        s2 += q4.x * a2.x + q4.y * a2.y + q4.z * a2.z + q4.w * a2.w;
        s3 += q4.x * a3.x + q4.y * a3.y + q4.z * a3.z + q4.w * a3.w;
      }
      float* srow = &S[i16 * 200 + kc];
      if (jj < cn) srow[jj] = s0;
      if (jj + 16 < cn) srow[jj + 16] = s1;
      if (jj + 32 < cn) srow[jj + 32] = s2;
      if (jj + 48 < cn) srow[jj + 48] = s3;
    }
    __syncthreads();
    {
      const int row = tid >> 4;
      const int lane = tid & 15;
      float* srow = &S[row * 200];
      float m = -3.4e38f;
      for (int j = lane; j < WHT; j += 16) m = fmaxf(m, srow[j]);
#pragma unroll
      for (int msk = 8; msk >= 1; msk >>= 1) m = fmaxf(m, __shfl_xor(m, msk, 16));
      float l = 0.f;
      for (int j = lane; j < WHT; j += 16) {
        float e = expf(srow[j] - m);
        srow[j] = e;
        l += e;
      }
#pragma unroll
      for (int msk = 8; msk >= 1; msk >>= 1) l += __shfl_xor(l, msk, 16);
      float inv = 1.f / l;
      for (int j = lane; j < WHT; j += 16) srow[j] *= inv;
    }
    float acc[4] = {0.f, 0.f, 0.f, 0.f};
    for (int vc = 0; vc < WHT; vc += 64) {
      const int cn = min(64, WHT - vc);
      __syncthreads();
#pragma unroll
      for (int r = 0; r < 4; r++) {
        int e = tid + r * 256;
        int j = e >> 4, f4 = (e & 15) * 4;
        int vrow = vc + j;
        float4 v = make_float4(0.f, 0.f, 0.f, 0.f);
        if (vrow < WHT)
          v = *(const float4*)(qkv + base + (size_t)vrow * 12288 + 1024 + f4);
        *(float4*)&Vs[j * 68 + f4] = v;
      }
      __syncthreads();
#pragma unroll 2
      for (int j4 = 0; j4 < cn; j4 += 4) {
        float v0 = Vs[(j4 + 0) * 68 + d];
        float v1 = Vs[(j4 + 1) * 68 + d];
        float v2 = Vs[(j4 + 2) * 68 + d];
        float v3 = Vs[(j4 + 3) * 68 + d];
#pragma unroll
        for (int u = 0; u < 4; u++) {
          float4 s4 = *(const float4*)&S[(qg + 4 * u) * 200 + vc + j4];
          acc[u] += s4.x * v0 + s4.y * v1 + s4.z * v2 + s4.w * v3;
        }
      }
    }
#pragma unroll
    for (int u = 0; u < 4; u++) {
      int i = qg + 4 * u;
      int w = qt * 16 + i;
      if (w < WHT)
        outA[(size_t)((1 + tq * WHT + w) * 8 + b) * CC + h * 64 + d] = acc[u];
    }
  }
}

// ---------------------------------------------------------------------------
// Final LN (token 0 only) + classifier head
// ---------------------------------------------------------------------------
__global__ __launch_bounds__(256)
void head_kernel(const float* __restrict__ X, const float* __restrict__ enw,
                 const float* __restrict__ enb, const float* __restrict__ fcw,
                 const float* __restrict__ fcb, float* __restrict__ out) {
  __shared__ float nx[512];
  __shared__ float red[8];
  const int b = blockIdx.x, tid = threadIdx.x;
  const float* x = X + (size_t)b * CC;
  float v0 = x[tid], v1 = x[tid + 256];
  float s = wave_reduce_sum(v0 + v1);
  if ((tid & 63) == 0) red[tid >> 6] = s;
  __syncthreads();
  float mean = (red[0] + red[1] + red[2] + red[3]) * (1.f / 512.f);
  float d0 = v0 - mean, d1 = v1 - mean;
  float vs = wave_reduce_sum(d0 * d0 + d1 * d1);
  if ((tid & 63) == 0) red[4 + (tid >> 6)] = vs;
  __syncthreads();
  float var = (red[4] + red[5] + red[6] + red[7]) * (1.f / 512.f);
  float inv = 1.0f / sqrtf(var + 1e-5f);
  nx[tid] = d0 * inv * enw[tid] + enb[tid];
  nx[tid + 256] = d1 * inv * enw[tid + 256] + enb[tid + 256];
  __syncthreads();
  if (tid < NCLS) {
    float acc = fcb[tid];
    for (int c = 0; c < 512; c++) acc += nx[c] * fcw[c * NCLS + tid];
    out[b * NCLS + tid] = acc;
  }
}

// ---------------------------------------------------------------------------
extern "C" void kernel_launch(void* const* d_in, const int* in_sizes, int n_in,
                              void* d_out, int out_size, void* d_ws, size_t ws_size,
                              hipStream_t stream) {
  (void)in_sizes; (void)n_in; (void)out_size; (void)ws_size;
  const float* src  = (const float*)d_in[0];
  const float* cw   = (const float*)d_in[1];
  const float* cb   = (const float*)d_in[2];
  const float* clst = (const float*)d_in[3];
  const float* pos  = (const float*)d_in[4];
  const float* Wt   = (const float*)d_in[5];
  const float* bt   = (const float*)d_in[6];
  const float* Wsp  = (const float*)d_in[7];
  const float* bsp  = (const float*)d_in[8];
  const float* Wo   = (const float*)d_in[9];
  const float* bo   = (const float*)d_in[10];
  const float* n1w  = (const float*)d_in[11];
  const float* n1b  = (const float*)d_in[12];
  const float* n2w  = (const float*)d_in[13];
  const float* n2b  = (const float*)d_in[14];
  const float* W1   = (const float*)d_in[15];
  const float* b1   = (const float*)d_in[16];
  const float* W2   = (const float*)d_in[17];
  const float* b2   = (const float*)d_in[18];
  const float* enw  = (const float*)d_in[19];
  const float* enb  = (const float*)d_in[20];
  const float* fcw  = (const float*)d_in[21];
  const float* fcb  = (const float*)d_in[22];

  float* ws = (float*)d_ws;
  const size_t TOKR = (size_t)3137 * 8;
  float* X0  = ws;                              // TOKR*512
  float* Ab  = X0 + TOKR * 512;                 // TOKR*512
  float* QKV = Ab + TOKR * 512;                 // TOKR*1536 (also FFN mid)
  float* CLS = QKV + TOKR * 1536;               // 8*512
  int*   IDX = (int*)(CLS + 8 * 512);           // 8*8*196*16 ints
  unsigned short* WT1 = (unsigned short*)(IDX + 8 * 8 * WHT * 16);  // 2048*512
  unsigned short* WT2 = WT1 + 2048 * 512;                           // 2048*512

  conv_kernel<<<3136, 256, 0, stream>>>(src, cw, cb, X0);
  cls_init_kernel<<<8, 512, 0, stream>>>(clst, X0);

  float* Xc = X0;
  int t = 16;
  const int FFN_CHUNK = 16384;
  for (int i = 0; i < 6; i++) {
    const int pk = (i & 1) ? 2 : 0;
    const int tp = t - pk;
    const int L = 1 + t * WHT;
    const int Lo = 1 + tp * WHT;
    const int M = L * 8, Mo = Lo * 8, My = tp * WHT * 8;

    ln_kernel<<<M, 256, 0, stream>>>(Xc, Ab, n1w + (size_t)i * 512, n1b + (size_t)i * 512,
                                     (i == 0) ? pos : nullptr);
    // sigma-critical: fp32 GEMM for Wt
    gemm_kernel<0, 0><<<dim3((M + 63) / 64, 24), 256, 0, stream>>>(
        Ab, Wt + (size_t)i * 512 * 1536, bt + (size_t)i * 1536, QKV, M, 1536, 512,
        nullptr);
    class_attn_kernel<<<64, 256, 0, stream>>>(QKV, CLS, L);
    temporal_attn_kernel<<<HH * BB * WHT, 256, 0, stream>>>(QKV, Ab, IDX, t, tp, pk);
    // Ws: bf16 MFMA
    wtrans_kernel<<<dim3(1536 / 32, 512 / 32), 256, 0, stream>>>(
        Wsp + (size_t)i * 512 * 1536, WT1, 1536, 512);
    mfma_gemm_kernel<0, 0><<<dim3((My + 127) / 128, 12), 256, 0, stream>>>(
        Ab, WT1, bsp + (size_t)i * 1536, QKV, My, 1536, 512, nullptr);
    copy_cls_kernel<<<8, 512, 0, stream>>>(CLS, Ab);
    spatial_attn3_kernel<<<64 * tp, 256, 0, stream>>>(QKV, Ab);
    if (pk > 0)
      pool_inplace_kernel<<<8 * WHT, 256, 0, stream>>>(Xc, IDX, tp);
    // Wo: bf16 MFMA + residual
    wtrans_kernel<<<dim3(512 / 32, 512 / 32), 256, 0, stream>>>(
        Wo + (size_t)i * 512 * 512, WT1, 512, 512);
    mfma_gemm_kernel<0, 1><<<dim3((Mo + 127) / 128, 4), 256, 0, stream>>>(
        Ab, WT1, bo + (size_t)i * 512, Xc, Mo, 512, 512, Xc);
    ln_kernel<<<Mo, 256, 0, stream>>>(Xc, Ab, n2w + (size_t)i * 512, n2b + (size_t)i * 512,
                                      nullptr);
    // FFN: bf16 MFMA (W1 relu -> mid fp32 in QKV region; W2 + residual)
    wtrans_kernel<<<dim3(2048 / 32, 512 / 32), 256, 0, stream>>>(
        W1 + (size_t)i * 512 * 2048, WT1, 2048, 512);
    wtrans_kernel<<<dim3(512 / 32, 2048 / 32), 256, 0, stream>>>(
        W2 + (size_t)i * 2048 * 512, WT2, 512, 2048);
    for (int off = 0; off < Mo; off += FFN_CHUNK) {
      int R = Mo - off;
      if (R > FFN_CHUNK) R = FFN_CHUNK;
      mfma_gemm_kernel<1, 0><<<dim3((R + 127) / 128, 16), 256, 0, stream>>>(
          Ab + (size_t)off * 512, WT1, b1 + (size_t)i * 2048, QKV, R, 2048, 512,
          nullptr);
      mfma_gemm_kernel<0, 1><<<dim3((R + 127) / 128, 4), 256, 0, stream>>>(
          QKV, WT2, b2 + (size_t)i * 512, Xc + (size_t)off * 512, R, 512, 2048,
          Xc + (size_t)off * 512);
    }
    t = tp;
  }
  head_kernel<<<8, 256, 0, stream>>>(Xc, enw, enb, fcw, fcb, (float*)d_out);
}

// Round 6
// 9903.590 us; speedup vs baseline: 5.4470x; 1.1874x over previous
//
#include <hip/hip_runtime.h>
#include <math.h>

// ---------------------------------------------------------------------------
// CompactVidTr forward.
//  - Wt (QKV) GEMM: split-bf16 MFMA (hi/lo decomposition, 3 MFMA terms) ->
//    fp32-class accuracy for the sigma-top-k ranking path.
//  - Ws/Wo/FFN GEMMs: plain bf16 MFMA (incremental-error paths).
//  - Attention/LN/conv: fp32 vector.
// Layout: token matrices row-major [row = l*B + b][C]; l=0 is cls. B=8, C=512.
//
// Workspace (261.9 MB < 268.4 MB):
//   X   : 3137*8 x 512  fp32   (51.4 MB)  residual stream, pooled IN PLACE
//   Ab  : 3137*8 x 512  fp32   (51.4 MB)  LN out / attention out staging
//   QKV : 3137*8 x 1536 fp32  (154.1 MB)  qkv GEMM out; reused as FFN mid
//   CLS : 8x512 fp32, IDX: 8*8*196*16 int (~0.8 MB)
//   WT1 : 2048*512 bf16 (2.1 MB)  weight scratch (Wt-hi / Ws / Wo / W1)
//   WT2 : 2048*512 bf16 (2.1 MB)  weight scratch (Wt-lo / W2)
// ---------------------------------------------------------------------------

#define BB 8
#define CC 512
#define HH 8
#define HD 64
#define WHT 196
#define NCLS 157

typedef short bf16x8 __attribute__((ext_vector_type(8)));
typedef float floatx4 __attribute__((ext_vector_type(4)));

__device__ __forceinline__ unsigned short f2bf(float f) {
  unsigned u = __float_as_uint(f);
  unsigned r = u + 0x7FFFu + ((u >> 16) & 1u);  // RNE
  return (unsigned short)(r >> 16);
}
__device__ __forceinline__ float bf2f(unsigned short h) {
  return __uint_as_float((unsigned)h << 16);
}

__device__ __forceinline__ float wave_reduce_sum(float v) {
#pragma unroll
  for (int o = 32; o > 0; o >>= 1) v += __shfl_down(v, o, 64);
  return v;
}
__device__ __forceinline__ float wave_reduce_max(float v) {
#pragma unroll
  for (int o = 32; o > 0; o >>= 1) v = fmaxf(v, __shfl_down(v, o, 64));
  return v;
}

// ---------------------------------------------------------------------------
// Patch-embed conv
// ---------------------------------------------------------------------------
__global__ __launch_bounds__(256)
void conv_kernel(const float* __restrict__ src, const float* __restrict__ cw,
                 const float* __restrict__ cb, float* __restrict__ X) {
  __shared__ float patch[8][776];
  const int tid = threadIdx.x;
  const int u0 = blockIdx.x * 8;
  for (int j = 0; j < 8; j++) {
    int u = u0 + j;
    int b = u & 7;
    int s = u >> 3;
    int tt = s / WHT;
    int w2 = s % WHT;
    int ph = w2 / 14, pw = w2 % 14;
    const float* sb = src + (size_t)b * (3 * 16 * 224 * 224) +
                      (size_t)tt * (224 * 224) + (size_t)(ph * 16) * 224 + pw * 16;
    for (int e = tid; e < 768; e += 256) {
      int ci = e >> 8;
      int rem = e & 255;
      int py = rem >> 4, px = rem & 15;
      patch[j][e] = sb[(size_t)ci * (16 * 224 * 224) + py * 224 + px];
    }
  }
  __syncthreads();
  float acc0[8] = {0, 0, 0, 0, 0, 0, 0, 0};
  float acc1[8] = {0, 0, 0, 0, 0, 0, 0, 0};
  for (int e0 = 0; e0 < 768; e0 += 4) {
    float4 w0 = *(const float4*)(cw + (size_t)tid * 768 + e0);
    float4 w1 = *(const float4*)(cw + (size_t)(tid + 256) * 768 + e0);
#pragma unroll
    for (int j = 0; j < 8; j++) {
      float4 p = *(const float4*)&patch[j][e0];
      acc0[j] += w0.x * p.x + w0.y * p.y + w0.z * p.z + w0.w * p.w;
      acc1[j] += w1.x * p.x + w1.y * p.y + w1.z * p.z + w1.w * p.w;
    }
  }
  float cb0 = cb[tid], cb1 = cb[tid + 256];
  for (int j = 0; j < 8; j++) {
    int u = u0 + j;
    X[(size_t)(8 + u) * CC + tid] = acc0[j] + cb0;
    X[(size_t)(8 + u) * CC + tid + 256] = acc1[j] + cb1;
  }
}

__global__ void cls_init_kernel(const float* __restrict__ clst, float* __restrict__ X) {
  X[(size_t)blockIdx.x * CC + threadIdx.x] = clst[threadIdx.x];
}

__global__ void copy_cls_kernel(const float* __restrict__ cls, float* __restrict__ A) {
  A[(size_t)blockIdx.x * CC + threadIdx.x] = cls[(size_t)blockIdx.x * CC + threadIdx.x];
}

// ---------------------------------------------------------------------------
// LayerNorm over C=512; one block per row; optional +pos (layer0 q-input)
// ---------------------------------------------------------------------------
__global__ __launch_bounds__(256)
void ln_kernel(const float* __restrict__ X, float* __restrict__ O,
               const float* __restrict__ w, const float* __restrict__ b,
               const float* __restrict__ pos) {
  __shared__ float red[8];
  const int row = blockIdx.x, tid = threadIdx.x;
  const float* x = X + (size_t)row * CC;
  float v0 = x[tid], v1 = x[tid + 256];
  float s = wave_reduce_sum(v0 + v1);
  if ((tid & 63) == 0) red[tid >> 6] = s;
  __syncthreads();
  float mean = (red[0] + red[1] + red[2] + red[3]) * (1.f / 512.f);
  float d0 = v0 - mean, d1 = v1 - mean;
  float vs = wave_reduce_sum(d0 * d0 + d1 * d1);
  if ((tid & 63) == 0) red[4 + (tid >> 6)] = vs;
  __syncthreads();
  float var = (red[4] + red[5] + red[6] + red[7]) * (1.f / 512.f);
  float inv = 1.0f / sqrtf(var + 1e-5f);
  float o0 = d0 * inv * w[tid] + b[tid];
  float o1 = d1 * inv * w[tid + 256] + b[tid + 256];
  if (pos) {
    const float* pr = pos + (size_t)(row >> 3) * CC;
    o0 += pr[tid];
    o1 += pr[tid + 256];
  }
  O[(size_t)row * CC + tid] = o0;
  O[(size_t)row * CC + tid + 256] = o1;
}

// ---------------------------------------------------------------------------
// Weight transpose + fp32->bf16 (plain): W [K][N] -> WT [N][K]
// ---------------------------------------------------------------------------
__global__ __launch_bounds__(256)
void wtrans_kernel(const float* __restrict__ W, unsigned short* __restrict__ WT,
                   int N, int K) {
  __shared__ float tile[32][33];
  const int tid = threadIdx.x;
  const int tx = tid & 31, ty = tid >> 5;
  const int n0 = blockIdx.x * 32, k0 = blockIdx.y * 32;
#pragma unroll
  for (int r = 0; r < 4; r++) {
    int kk = ty + r * 8;
    tile[kk][tx] = W[(size_t)(k0 + kk) * N + n0 + tx];
  }
  __syncthreads();
#pragma unroll
  for (int r = 0; r < 4; r++) {
    int nn = ty + r * 8;
    WT[(size_t)(n0 + nn) * K + k0 + tx] = f2bf(tile[tx][nn]);
  }
}

// ---------------------------------------------------------------------------
// Weight transpose + split fp32 -> (hi, lo) bf16: W [K][N] -> WThi/WTlo [N][K]
// ---------------------------------------------------------------------------
__global__ __launch_bounds__(256)
void wtrans_split_kernel(const float* __restrict__ W,
                         unsigned short* __restrict__ WThi,
                         unsigned short* __restrict__ WTlo, int N, int K) {
  __shared__ float tile[32][33];
  const int tid = threadIdx.x;
  const int tx = tid & 31, ty = tid >> 5;
  const int n0 = blockIdx.x * 32, k0 = blockIdx.y * 32;
#pragma unroll
  for (int r = 0; r < 4; r++) {
    int kk = ty + r * 8;
    tile[kk][tx] = W[(size_t)(k0 + kk) * N + n0 + tx];
  }
  __syncthreads();
#pragma unroll
  for (int r = 0; r < 4; r++) {
    int nn = ty + r * 8;
    float w = tile[tx][nn];
    unsigned short hi = f2bf(w);
    unsigned short lo = f2bf(w - bf2f(hi));
    WThi[(size_t)(n0 + nn) * K + k0 + tx] = hi;
    WTlo[(size_t)(n0 + nn) * K + k0 + tx] = lo;
  }
}

// ---------------------------------------------------------------------------
// Plain bf16 MFMA GEMM: C = A(M,K) @ W(K,N) + bias [+relu] [+residual]
// A fp32 (converted in staging), WT = bf16 [N][K] pre-transposed.
// 128x128 tile, 4 waves, each 64x64 via 4x4 mfma_f32_16x16x32_bf16.
// ---------------------------------------------------------------------------
template <int RELU, int RES>
__global__ __launch_bounds__(256)
void mfma_gemm_kernel(const float* __restrict__ A,
                      const unsigned short* __restrict__ WT,
                      const float* __restrict__ bias, float* __restrict__ Cout,
                      int M, int N, int K, const float* __restrict__ resid) {
  __shared__ unsigned short AsU[128 * 40];
  __shared__ unsigned short BsU[128 * 40];
  const int tid = threadIdx.x;
  const int wave = tid >> 6, lane = tid & 63;
  const int quad = lane >> 4, l16 = lane & 15;
  const int wrow = (wave >> 1) * 64, wcol = (wave & 1) * 64;
  const int m0 = blockIdx.x * 128, n0 = blockIdx.y * 128;

  floatx4 acc[4][4];
#pragma unroll
  for (int i = 0; i < 4; i++)
#pragma unroll
    for (int j = 0; j < 4; j++) acc[i][j] = (floatx4){0.f, 0.f, 0.f, 0.f};

  for (int k0 = 0; k0 < K; k0 += 32) {
#pragma unroll
    for (int r = 0; r < 4; r++) {
      int e = (tid + r * 256) * 4;
      int row = e >> 5, col = e & 31;
      int gm = m0 + row;
      float4 v = make_float4(0.f, 0.f, 0.f, 0.f);
      if (gm < M) v = *(const float4*)(A + (size_t)gm * K + k0 + col);
      ushort4 o;
      o.x = f2bf(v.x); o.y = f2bf(v.y); o.z = f2bf(v.z); o.w = f2bf(v.w);
      *(ushort4*)&AsU[row * 40 + col] = o;
    }
#pragma unroll
    for (int r = 0; r < 4; r++) {
      int e = (tid + r * 256) * 4;
      int n = e >> 5, k = e & 31;
      ushort4 w = *(const ushort4*)(WT + (size_t)(n0 + n) * K + k0 + k);
      *(ushort4*)&BsU[n * 40 + k] = w;
    }
    __syncthreads();
    bf16x8 af[4], bf[4];
#pragma unroll
    for (int i = 0; i < 4; i++)
      af[i] = *(const bf16x8*)&AsU[(wrow + i * 16 + l16) * 40 + quad * 8];
#pragma unroll
    for (int j = 0; j < 4; j++)
      bf[j] = *(const bf16x8*)&BsU[(wcol + j * 16 + l16) * 40 + quad * 8];
#pragma unroll
    for (int i = 0; i < 4; i++)
#pragma unroll
      for (int j = 0; j < 4; j++)
        acc[i][j] = __builtin_amdgcn_mfma_f32_16x16x32_bf16(af[i], bf[j],
                                                            acc[i][j], 0, 0, 0);
    __syncthreads();
  }
#pragma unroll
  for (int i = 0; i < 4; i++) {
#pragma unroll
    for (int p = 0; p < 4; p++) {
      int gm = m0 + wrow + i * 16 + quad * 4 + p;
      if (gm >= M) continue;
#pragma unroll
      for (int j = 0; j < 4; j++) {
        int gn = n0 + wcol + j * 16 + l16;
        float v = acc[i][j][p] + bias[gn];
        if (RELU) v = fmaxf(v, 0.f);
        if (RES == 1) v += resid[(size_t)gm * N + gn];
        Cout[(size_t)gm * N + gn] = v;
      }
    }
  }
}

// ---------------------------------------------------------------------------
// Split-bf16 MFMA GEMM (sigma-safe, ~1e-5 relative error):
// C = Ahi@Bhi + Ahi@Blo + Alo@Bhi + bias.  A fp32 split in staging; B from
// pre-split WThi/WTlo [N][K]. 48 MFMA per 32-wide K-tile; 40 KB LDS.
// ---------------------------------------------------------------------------
__global__ __launch_bounds__(256)
void mfma_gemm3_kernel(const float* __restrict__ A,
                       const unsigned short* __restrict__ WThi,
                       const unsigned short* __restrict__ WTlo,
                       const float* __restrict__ bias, float* __restrict__ Cout,
                       int M, int N, int K) {
  __shared__ unsigned short AsHi[128 * 40];
  __shared__ unsigned short AsLo[128 * 40];
  __shared__ unsigned short BsHi[128 * 40];
  __shared__ unsigned short BsLo[128 * 40];
  const int tid = threadIdx.x;
  const int wave = tid >> 6, lane = tid & 63;
  const int quad = lane >> 4, l16 = lane & 15;
  const int wrow = (wave >> 1) * 64, wcol = (wave & 1) * 64;
  const int m0 = blockIdx.x * 128, n0 = blockIdx.y * 128;

  floatx4 acc[4][4];
#pragma unroll
  for (int i = 0; i < 4; i++)
#pragma unroll
    for (int j = 0; j < 4; j++) acc[i][j] = (floatx4){0.f, 0.f, 0.f, 0.f};

  for (int k0 = 0; k0 < K; k0 += 32) {
#pragma unroll
    for (int r = 0; r < 4; r++) {
      int e = (tid + r * 256) * 4;
      int row = e >> 5, col = e & 31;
      int gm = m0 + row;
      float4 v = make_float4(0.f, 0.f, 0.f, 0.f);
      if (gm < M) v = *(const float4*)(A + (size_t)gm * K + k0 + col);
      ushort4 hi, lo;
      hi.x = f2bf(v.x); lo.x = f2bf(v.x - bf2f(hi.x));
      hi.y = f2bf(v.y); lo.y = f2bf(v.y - bf2f(hi.y));
      hi.z = f2bf(v.z); lo.z = f2bf(v.z - bf2f(hi.z));
      hi.w = f2bf(v.w); lo.w = f2bf(v.w - bf2f(hi.w));
      *(ushort4*)&AsHi[row * 40 + col] = hi;
      *(ushort4*)&AsLo[row * 40 + col] = lo;
    }
#pragma unroll
    for (int r = 0; r < 4; r++) {
      int e = (tid + r * 256) * 4;
      int n = e >> 5, k = e & 31;
      *(ushort4*)&BsHi[n * 40 + k] =
          *(const ushort4*)(WThi + (size_t)(n0 + n) * K + k0 + k);
      *(ushort4*)&BsLo[n * 40 + k] =
          *(const ushort4*)(WTlo + (size_t)(n0 + n) * K + k0 + k);
    }
    __syncthreads();
    bf16x8 ah[4], al[4], bh[4], bl[4];
#pragma unroll
    for (int i = 0; i < 4; i++) {
      ah[i] = *(const bf16x8*)&AsHi[(wrow + i * 16 + l16) * 40 + quad * 8];
      al[i] = *(const bf16x8*)&AsLo[(wrow + i * 16 + l16) * 40 + quad * 8];
    }
#pragma unroll
    for (int j = 0; j < 4; j++) {
      bh[j] = *(const bf16x8*)&BsHi[(wcol + j * 16 + l16) * 40 + quad * 8];
      bl[j] = *(const bf16x8*)&BsLo[(wcol + j * 16 + l16) * 40 + quad * 8];
    }
#pragma unroll
    for (int i = 0; i < 4; i++)
#pragma unroll
      for (int j = 0; j < 4; j++) {
        acc[i][j] = __builtin_amdgcn_mfma_f32_16x16x32_bf16(ah[i], bh[j],
                                                            acc[i][j], 0, 0, 0);
        acc[i][j] = __builtin_amdgcn_mfma_f32_16x16x32_bf16(ah[i], bl[j],
                                                            acc[i][j], 0, 0, 0);
        acc[i][j] = __builtin_amdgcn_mfma_f32_16x16x32_bf16(al[i], bh[j],
                                                            acc[i][j], 0, 0, 0);
      }
    __syncthreads();
  }
#pragma unroll
  for (int i = 0; i < 4; i++) {
#pragma unroll
    for (int p = 0; p < 4; p++) {
      int gm = m0 + wrow + i * 16 + quad * 4 + p;
      if (gm >= M) continue;
#pragma unroll
      for (int j = 0; j < 4; j++) {
        int gn = n0 + wcol + j * 16 + l16;
        Cout[(size_t)gm * N + gn] = acc[i][j][p] + bias[gn];
      }
    }
  }
}

// ---------------------------------------------------------------------------
// Class attention
// ---------------------------------------------------------------------------
__global__ __launch_bounds__(256)
void class_attn_kernel(const float* __restrict__ qkv, float* __restrict__ cls, int L) {
  __shared__ float q[64];
  __shared__ float sc[3200];
  __shared__ float red[8];
  __shared__ float pv[256];
  const int h = blockIdx.x & 7, b = blockIdx.x >> 3;
  const int tid = threadIdx.x;
  if (tid < 64) q[tid] = qkv[(size_t)b * 1536 + h * 64 + tid] * 0.125f;
  __syncthreads();
  float lmax = -3.4e38f;
  for (int l = tid; l < L; l += 256) {
    const float* kr = qkv + (size_t)(l * 8 + b) * 1536 + 512 + h * 64;
    float s = 0;
#pragma unroll 8
    for (int d2 = 0; d2 < 64; d2++) s += q[d2] * kr[d2];
    sc[l] = s;
    lmax = fmaxf(lmax, s);
  }
  lmax = wave_reduce_max(lmax);
  if ((tid & 63) == 0) red[tid >> 6] = lmax;
  __syncthreads();
  float gmax = fmaxf(fmaxf(red[0], red[1]), fmaxf(red[2], red[3]));
  float lsum = 0;
  for (int l = tid; l < L; l += 256) {
    float e = expf(sc[l] - gmax);
    sc[l] = e;
    lsum += e;
  }
  lsum = wave_reduce_sum(lsum);
  if ((tid & 63) == 0) red[4 + (tid >> 6)] = lsum;
  __syncthreads();
  float gsum = red[4] + red[5] + red[6] + red[7];
  const int g = tid >> 6, d = tid & 63;
  float acc = 0;
  for (int l = g; l < L; l += 4)
    acc += sc[l] * qkv[(size_t)(l * 8 + b) * 1536 + 1024 + h * 64 + d];
  pv[g * 64 + d] = acc;
  __syncthreads();
  if (g == 0) {
    float tot = pv[d] + pv[64 + d] + pv[128 + d] + pv[192 + d];
    cls[b * CC + h * 64 + d] = tot / gsum;
  }
}

// ---------------------------------------------------------------------------
// Temporal attention + sigma top-k pooling (fp32 — rank-critical).
// ---------------------------------------------------------------------------
__global__ __launch_bounds__(256)
void temporal_attn_kernel(const float* __restrict__ qkv, float* __restrict__ Y,
                          int* __restrict__ idxbuf, int t, int tp, int pk) {
  __shared__ float qs[16 * 65], ks[16 * 65], vs[16 * 65];
  __shared__ float a[16 * 17];
  __shared__ float sig[16];
  __shared__ int keepf[16];
  __shared__ int klist[16];
  const int g = blockIdx.x;
  const int w = g % WHT;
  const int bb = (g / WHT) & 7;
  const int h = g / (WHT * 8);
  const int tid = threadIdx.x;
  const int td = t * 64;
  for (int e = tid; e < td; e += 256) {
    int tt = e >> 6, d = e & 63;
    size_t rb = (size_t)((1 + tt * WHT + w) * 8 + bb) * 1536 + h * 64 + d;
    qs[tt * 65 + d] = qkv[rb] * 0.125f;
    ks[tt * 65 + d] = qkv[rb + 512];
    vs[tt * 65 + d] = qkv[rb + 1024];
  }
  __syncthreads();
  if (tid < t * t) {
    int qi = tid / t, ki = tid % t;
    const float* qp = &qs[qi * 65];
    const float* kp = &ks[ki * 65];
    float s = 0;
#pragma unroll 8
    for (int d2 = 0; d2 < 64; d2++) s += qp[d2] * kp[d2];
    a[qi * 17 + ki] = s;
  }
  __syncthreads();
  if (tid < t) {
    float* row = &a[tid * 17];
    float m = row[0];
    for (int k2 = 1; k2 < t; k2++) m = fmaxf(m, row[k2]);
    float sum = 0;
    for (int k2 = 0; k2 < t; k2++) {
      float e2 = expf(row[k2] - m);
      row[k2] = e2;
      sum += e2;
    }
    float inv = 1.f / sum;
    for (int k2 = 0; k2 < t; k2++) row[k2] *= inv;
  }
  __syncthreads();
  if (pk > 0) {
    if (tid < t) {
      const float* row = &a[tid * 17];
      float mean = 0;
      for (int k2 = 0; k2 < t; k2++) mean += row[k2];
      mean /= (float)t;
      float var = 0;
      for (int k2 = 0; k2 < t; k2++) {
        float dl = row[k2] - mean;
        var += dl * dl;
      }
      var /= (float)(t - 1);
      sig[tid] = sqrtf(var);
    }
    __syncthreads();
    if (tid < t) {
      float sv = sig[tid];
      int r = 0;
      for (int q2 = 0; q2 < t; q2++) {
        float so = sig[q2];
        if (so > sv || (so == sv && q2 < tid)) r++;
      }
      keepf[tid] = (r < tp) ? 1 : 0;
    }
    __syncthreads();
    if (tid < t && keepf[tid]) {
      int ppos = 0;
      for (int q2 = 0; q2 < tid; q2++) ppos += keepf[q2];
      klist[ppos] = tid;
      idxbuf[((h * 8 + bb) * WHT + w) * 16 + ppos] = tid;
    }
  } else {
    if (tid < t) klist[tid] = tid;
  }
  __syncthreads();
  const int gq = tid >> 6, d = tid & 63;
  for (int qi = gq; qi < tp; qi += 4) {
    int qq = klist[qi];
    const float* arow = &a[qq * 17];
    float acc = 0;
    for (int k2 = 0; k2 < t; k2++) acc += arow[k2] * vs[k2 * 65 + d];
    Y[(size_t)((qi * WHT + w) * 8 + bb) * CC + h * 64 + d] = acc;
  }
}

// ---------------------------------------------------------------------------
// In-place temporal pooling of the residual stream X.
// ---------------------------------------------------------------------------
__global__ __launch_bounds__(256)
void pool_inplace_kernel(float* __restrict__ X, const int* __restrict__ idxbuf,
                         int tp) {
  const int b = blockIdx.x & 7;
  const int w = blockIdx.x >> 3;
  const int tid = threadIdx.x;
  const int c0 = tid, c1 = tid + 256;
  const int h0 = c0 >> 6, h1 = c1 >> 6;
  const int ib0 = ((h0 * 8 + b) * WHT + w) * 16;
  const int ib1 = ((h1 * 8 + b) * WHT + w) * 16;
  for (int q = 0; q < tp; q++) {
    int s0 = idxbuf[ib0 + q];
    int s1 = idxbuf[ib1 + q];
    size_t drow = (size_t)((1 + q * WHT + w) * 8 + b) * CC;
    if (s0 != q) {
      size_t srow = (size_t)((1 + s0 * WHT + w) * 8 + b) * CC;
      X[drow + c0] = X[srow + c0];
    }
    if (s1 != q) {
      size_t srow = (size_t)((1 + s1 * WHT + w) * 8 + b) * CC;
      X[drow + c1] = X[srow + c1];
    }
  }
}

// ---------------------------------------------------------------------------
// Spatial attention v3 (register-bounded)
// ---------------------------------------------------------------------------
__global__ __launch_bounds__(256)
void spatial_attn3_kernel(const float* __restrict__ qkv, float* __restrict__ outA) {
  __shared__ float Qs[16 * 68];
  __shared__ float Ks[64 * 68];
  __shared__ float Vs[64 * 68];
  __shared__ float S[16 * 200];
  const int blk = blockIdx.x;
  const int h = blk & 7;
  const int b = (blk >> 3) & 7;
  const int tq = blk >> 6;
  const int tid = threadIdx.x;
  const size_t base = (size_t)((size_t)tq * WHT * 8 + b) * 1536 + h * 64;

  const int i16 = tid >> 4;
  const int jj = tid & 15;
  const int qg = tid >> 6;
  const int d = tid & 63;

  for (int qt = 0; qt < 13; qt++) {
    __syncthreads();
    {
      int i = tid >> 4, f4 = (tid & 15) * 4;
      int w = qt * 16 + i;
      float4 v = make_float4(0.f, 0.f, 0.f, 0.f);
      if (w < WHT) {
        v = *(const float4*)(qkv + base + (size_t)w * 12288 + f4);
        v.x *= 0.125f; v.y *= 0.125f; v.z *= 0.125f; v.w *= 0.125f;
      }
      *(float4*)&Qs[i * 68 + f4] = v;
    }
    for (int kc = 0; kc < WHT; kc += 64) {
      const int cn = min(64, WHT - kc);
      __syncthreads();
#pragma unroll
      for (int r = 0; r < 4; r++) {
        int e = tid + r * 256;
        int j = e >> 4, f4 = (e & 15) * 4;
        int krow = kc + j;
        float4 v = make_float4(0.f, 0.f, 0.f, 0.f);
        if (krow < WHT)
          v = *(const float4*)(qkv + base + (size_t)krow * 12288 + 512 + f4);
        *(float4*)&Ks[j * 68 + f4] = v;
      }
      __syncthreads();
      float s0 = 0.f, s1 = 0.f, s2 = 0.f, s3 = 0.f;
      const float* qrow = &Qs[i16 * 68];
      const float* k0 = &Ks[jj * 68];
      const float* k1 = &Ks[(jj + 16) * 68];
      const float* k2 = &Ks[(jj + 32) * 68];
      const float* k3 = &Ks[(jj + 48) * 68];
#pragma unroll 2
      for (int d2 = 0; d2 < 64; d2 += 4) {
        float4 q4 = *(const float4*)(qrow + d2);
        float4 a0 = *(const float4*)(k0 + d2);
        float4 a1 = *(const float4*)(k1 + d2);
        float4 a2 = *(const float4*)(k2 + d2);
        float4 a3 = *(const float4*)(k3 + d2);
        s0 += q4.x * a0.x + q4.y * a0.y + q4.z * a0.z + q4.w * a0.w;
        s1 += q4.x * a1.x + q4.y * a1.y + q4.z * a1.z + q4.w * a1.w;
        s2 += q4.x * a2.x + q4.y * a2.y + q4.z * a2.z + q4.w * a2.w;
        s3 += q4.x * a3.x + q4.y * a3.y + q4.z * a3.z + q4.w * a3.w;
      }
      float* srow = &S[i16 * 200 + kc];
      if (jj < cn) srow[jj] = s0;
      if (jj + 16 < cn) srow[jj + 16] = s1;
      if (jj + 32 < cn) srow[jj + 32] = s2;
      if (jj + 48 < cn) srow[jj + 48] = s3;
    }
    __syncthreads();
    {
      const int row = tid >> 4;
      const int lane = tid & 15;
      float* srow = &S[row * 200];
      float m = -3.4e38f;
      for (int j = lane; j < WHT; j += 16) m = fmaxf(m, srow[j]);
#pragma unroll
      for (int msk = 8; msk >= 1; msk >>= 1) m = fmaxf(m, __shfl_xor(m, msk, 16));
      float l = 0.f;
      for (int j = lane; j < WHT; j += 16) {
        float e = expf(srow[j] - m);
        srow[j] = e;
        l += e;
      }
#pragma unroll
      for (int msk = 8; msk >= 1; msk >>= 1) l += __shfl_xor(l, msk, 16);
      float inv = 1.f / l;
      for (int j = lane; j < WHT; j += 16) srow[j] *= inv;
    }
    float acc[4] = {0.f, 0.f, 0.f, 0.f};
    for (int vc = 0; vc < WHT; vc += 64) {
      const int cn = min(64, WHT - vc);
      __syncthreads();
#pragma unroll
      for (int r = 0; r < 4; r++) {
        int e = tid + r * 256;
        int j = e >> 4, f4 = (e & 15) * 4;
        int vrow = vc + j;
        float4 v = make_float4(0.f, 0.f, 0.f, 0.f);
        if (vrow < WHT)
          v = *(const float4*)(qkv + base + (size_t)vrow * 12288 + 1024 + f4);
        *(float4*)&Vs[j * 68 + f4] = v;
      }
      __syncthreads();
#pragma unroll 2
      for (int j4 = 0; j4 < cn; j4 += 4) {
        float v0 = Vs[(j4 + 0) * 68 + d];
        float v1 = Vs[(j4 + 1) * 68 + d];
        float v2 = Vs[(j4 + 2) * 68 + d];
        float v3 = Vs[(j4 + 3) * 68 + d];
#pragma unroll
        for (int u = 0; u < 4; u++) {
          float4 s4 = *(const float4*)&S[(qg + 4 * u) * 200 + vc + j4];
          acc[u] += s4.x * v0 + s4.y * v1 + s4.z * v2 + s4.w * v3;
        }
      }
    }
#pragma unroll
    for (int u = 0; u < 4; u++) {
      int i = qg + 4 * u;
      int w = qt * 16 + i;
      if (w < WHT)
        outA[(size_t)((1 + tq * WHT + w) * 8 + b) * CC + h * 64 + d] = acc[u];
    }
  }
}

// ---------------------------------------------------------------------------
// Final LN (token 0 only) + classifier head
// ---------------------------------------------------------------------------
__global__ __launch_bounds__(256)
void head_kernel(const float* __restrict__ X, const float* __restrict__ enw,
                 const float* __restrict__ enb, const float* __restrict__ fcw,
                 const float* __restrict__ fcb, float* __restrict__ out) {
  __shared__ float nx[512];
  __shared__ float red[8];
  const int b = blockIdx.x, tid = threadIdx.x;
  const float* x = X + (size_t)b * CC;
  float v0 = x[tid], v1 = x[tid + 256];
  float s = wave_reduce_sum(v0 + v1);
  if ((tid & 63) == 0) red[tid >> 6] = s;
  __syncthreads();
  float mean = (red[0] + red[1] + red[2] + red[3]) * (1.f / 512.f);
  float d0 = v0 - mean, d1 = v1 - mean;
  float vs = wave_reduce_sum(d0 * d0 + d1 * d1);
  if ((tid & 63) == 0) red[4 + (tid >> 6)] = vs;
  __syncthreads();
  float var = (red[4] + red[5] + red[6] + red[7]) * (1.f / 512.f);
  float inv = 1.0f / sqrtf(var + 1e-5f);
  nx[tid] = d0 * inv * enw[tid] + enb[tid];
  nx[tid + 256] = d1 * inv * enw[tid + 256] + enb[tid + 256];
  __syncthreads();
  if (tid < NCLS) {
    float acc = fcb[tid];
    for (int c = 0; c < 512; c++) acc += nx[c] * fcw[c * NCLS + tid];
    out[b * NCLS + tid] = acc;
  }
}

// ---------------------------------------------------------------------------
extern "C" void kernel_launch(void* const* d_in, const int* in_sizes, int n_in,
                              void* d_out, int out_size, void* d_ws, size_t ws_size,
                              hipStream_t stream) {
  (void)in_sizes; (void)n_in; (void)out_size; (void)ws_size;
  const float* src  = (const float*)d_in[0];
  const float* cw   = (const float*)d_in[1];
  const float* cb   = (const float*)d_in[2];
  const float* clst = (const float*)d_in[3];
  const float* pos  = (const float*)d_in[4];
  const float* Wt   = (const float*)d_in[5];
  const float* bt   = (const float*)d_in[6];
  const float* Wsp  = (const float*)d_in[7];
  const float* bsp  = (const float*)d_in[8];
  const float* Wo   = (const float*)d_in[9];
  const float* bo   = (const float*)d_in[10];
  const float* n1w  = (const float*)d_in[11];
  const float* n1b  = (const float*)d_in[12];
  const float* n2w  = (const float*)d_in[13];
  const float* n2b  = (const float*)d_in[14];
  const float* W1   = (const float*)d_in[15];
  const float* b1   = (const float*)d_in[16];
  const float* W2   = (const float*)d_in[17];
  const float* b2   = (const float*)d_in[18];
  const float* enw  = (const float*)d_in[19];
  const float* enb  = (const float*)d_in[20];
  const float* fcw  = (const float*)d_in[21];
  const float* fcb  = (const float*)d_in[22];

  float* ws = (float*)d_ws;
  const size_t TOKR = (size_t)3137 * 8;
  float* X0  = ws;                              // TOKR*512
  float* Ab  = X0 + TOKR * 512;                 // TOKR*512
  float* QKV = Ab + TOKR * 512;                 // TOKR*1536 (also FFN mid)
  float* CLS = QKV + TOKR * 1536;               // 8*512
  int*   IDX = (int*)(CLS + 8 * 512);           // 8*8*196*16 ints
  unsigned short* WT1 = (unsigned short*)(IDX + 8 * 8 * WHT * 16);  // 2048*512
  unsigned short* WT2 = WT1 + 2048 * 512;                           // 2048*512

  conv_kernel<<<3136, 256, 0, stream>>>(src, cw, cb, X0);
  cls_init_kernel<<<8, 512, 0, stream>>>(clst, X0);

  float* Xc = X0;
  int t = 16;
  const int FFN_CHUNK = 16384;
  for (int i = 0; i < 6; i++) {
    const int pk = (i & 1) ? 2 : 0;
    const int tp = t - pk;
    const int L = 1 + t * WHT;
    const int Lo = 1 + tp * WHT;
    const int M = L * 8, Mo = Lo * 8, My = tp * WHT * 8;

    ln_kernel<<<M, 256, 0, stream>>>(Xc, Ab, n1w + (size_t)i * 512, n1b + (size_t)i * 512,
                                     (i == 0) ? pos : nullptr);
    // sigma-critical Wt: split-bf16 MFMA (hi/lo), fp32-class accuracy
    wtrans_split_kernel<<<dim3(1536 / 32, 512 / 32), 256, 0, stream>>>(
        Wt + (size_t)i * 512 * 1536, WT1, WT2, 1536, 512);
    mfma_gemm3_kernel<<<dim3((M + 127) / 128, 12), 256, 0, stream>>>(
        Ab, WT1, WT2, bt + (size_t)i * 1536, QKV, M, 1536, 512);
    class_attn_kernel<<<64, 256, 0, stream>>>(QKV, CLS, L);
    temporal_attn_kernel<<<HH * BB * WHT, 256, 0, stream>>>(QKV, Ab, IDX, t, tp, pk);
    // Ws: plain bf16 MFMA
    wtrans_kernel<<<dim3(1536 / 32, 512 / 32), 256, 0, stream>>>(
        Wsp + (size_t)i * 512 * 1536, WT1, 1536, 512);
    mfma_gemm_kernel<0, 0><<<dim3((My + 127) / 128, 12), 256, 0, stream>>>(
        Ab, WT1, bsp + (size_t)i * 1536, QKV, My, 1536, 512, nullptr);
    copy_cls_kernel<<<8, 512, 0, stream>>>(CLS, Ab);
    spatial_attn3_kernel<<<64 * tp, 256, 0, stream>>>(QKV, Ab);
    if (pk > 0)
      pool_inplace_kernel<<<8 * WHT, 256, 0, stream>>>(Xc, IDX, tp);
    // Wo: plain bf16 MFMA + residual
    wtrans_kernel<<<dim3(512 / 32, 512 / 32), 256, 0, stream>>>(
        Wo + (size_t)i * 512 * 512, WT1, 512, 512);
    mfma_gemm_kernel<0, 1><<<dim3((Mo + 127) / 128, 4), 256, 0, stream>>>(
        Ab, WT1, bo + (size_t)i * 512, Xc, Mo, 512, 512, Xc);
    ln_kernel<<<Mo, 256, 0, stream>>>(Xc, Ab, n2w + (size_t)i * 512, n2b + (size_t)i * 512,
                                      nullptr);
    // FFN: plain bf16 MFMA
    wtrans_kernel<<<dim3(2048 / 32, 512 / 32), 256, 0, stream>>>(
        W1 + (size_t)i * 512 * 2048, WT1, 2048, 512);
    wtrans_kernel<<<dim3(512 / 32, 2048 / 32), 256, 0, stream>>>(
        W2 + (size_t)i * 2048 * 512, WT2, 512, 2048);
    for (int off = 0; off < Mo; off += FFN_CHUNK) {
      int R = Mo - off;
      if (R > FFN_CHUNK) R = FFN_CHUNK;
      mfma_gemm_kernel<1, 0><<<dim3((R + 127) / 128, 16), 256, 0, stream>>>(
          Ab + (size_t)off * 512, WT1, b1 + (size_t)i * 2048, QKV, R, 2048, 512,
          nullptr);
      mfma_gemm_kernel<0, 1><<<dim3((R + 127) / 128, 4), 256, 0, stream>>>(
          QKV, WT2, b2 + (size_t)i * 512, Xc + (size_t)off * 512, R, 512, 2048,
          Xc + (size_t)off * 512);
    }
    t = tp;
  }
  head_kernel<<<8, 256, 0, stream>>>(Xc, enw, enb, fcw, fcb, (float*)d_out);
}